// Round 6
// baseline (154.775 us; speedup 1.0000x reference)
//
#include <hip/hip_runtime.h>
#include <stdint.h>

typedef unsigned short u16;
typedef unsigned long long u64;
typedef __attribute__((ext_vector_type(8))) short short8;
typedef __attribute__((ext_vector_type(4))) float f32x4;

#define MFMA16 __builtin_amdgcn_mfma_f32_16x16x32_bf16

#define B_ 1024
#define N_ 64
#define MTOT (B_ * N_)   // 65536

__device__ __forceinline__ u16 f2bf(float f) {
  union { float f; uint32_t u; } v; v.f = f;
  uint32_t r = v.u + 0x7FFFu + ((v.u >> 16) & 1u);
  return (u16)(r >> 16);
}

union U8 { short8 v; u16 u[8]; };
union U4 { u64 v; u16 u[4]; };

__device__ __forceinline__ void cp16(const void* g, void* l) {
  __builtin_amdgcn_global_load_lds(
      (const __attribute__((address_space(1))) void*)g,
      (__attribute__((address_space(3))) void*)l, 16, 0, 0);
}

// ---------------------------------------------------------------------------
// L1: prep1 (blocks 0..255) + wconv (blocks 256..367)
// ---------------------------------------------------------------------------
__global__ __launch_bounds__(256) void k_prep1_wconv(
    const float* __restrict__ Wc, const float* __restrict__ Wo,
    const float* __restrict__ bo, const float* __restrict__ bc,
    float* __restrict__ M1, float* __restrict__ bv,
    const float* __restrict__ W1, const float* __restrict__ W2,
    const float* __restrict__ Wq, const float* __restrict__ Wk,
    u16* o1, u16* o2, u16* oq, u16* ok) {
  const int bid = blockIdx.x, tid = threadIdx.x;
  if (bid < 256) {
    // prep1: M1 = Wc @ Wo, bv = bc + Wc @ bo
    __shared__ float wcr[256];
    __shared__ float red[4];
    const int j = bid, d = tid;
    wcr[d] = Wc[j * 256 + d];
    __syncthreads();
    float acc = 0.f;
    for (int i = 0; i < 256; i++) acc += wcr[i] * Wo[i * 256 + d];
    M1[j * 256 + d] = acc;
    float p = wcr[d] * bo[d];
    for (int off = 32; off >= 1; off >>= 1) p += __shfl_xor(p, off);
    if ((d & 63) == 0) red[d >> 6] = p;
    __syncthreads();
    if (d == 0) bv[j] = bc[j] + red[0] + red[1] + red[2] + red[3];
  } else {
    int off8 = (bid - 256) * 256 + tid;
    const float* src; u16* dst;
    if      (off8 <  4096) { src = W1; dst = o1; }
    else if (off8 < 12288) { src = W2; dst = o2; off8 -= 4096; }
    else if (off8 < 20480) { src = Wq; dst = oq; off8 -= 12288; }
    else                   { src = Wk; dst = ok; off8 -= 20480; }
    const int e = off8 * 8;
    f32x4 a = *(const f32x4*)(src + e);
    f32x4 b = *(const f32x4*)(src + e + 4);
    U8 pk;
#pragma unroll
    for (int j = 0; j < 4; j++) { pk.u[j] = f2bf(a[j]); pk.u[4 + j] = f2bf(b[j]); }
    *(short8*)(dst + e) = pk.v;
  }
}

// ---------------------------------------------------------------------------
// L2: gemm1 (blocks 0..511; 128x256 tile, K=128, swizzled LDS) +
//     prep2 (blocks 512..527: Wzf = W3@M1, bz = W3@bvchain + Wzf@bvw)
// ---------------------------------------------------------------------------
__global__ __launch_bounds__(256, 3) void k_gemm1_prep2(
    const float* __restrict__ obs, const u16* __restrict__ W1b,
    const float* __restrict__ b1, u16* __restrict__ x1,
    const float* __restrict__ W3, const float* __restrict__ M1,
    const float* __restrict__ bvchain, const float* __restrict__ bvw,
    float* __restrict__ Wzf, float* __restrict__ bz) {
  __shared__ char smem[49152];
  const int tid = threadIdx.x;
  if (blockIdx.x >= 512) {
    float* w3r = (float*)smem;
    float* red = (float*)(smem + 1024);
    const int a = blockIdx.x - 512, d = tid;
    w3r[d] = W3[a * 256 + d];
    __syncthreads();
    float acc = 0.f;
    for (int j = 0; j < 256; j++) acc += w3r[j] * M1[j * 256 + d];
    Wzf[a * 256 + d] = acc;
    float p = w3r[d] * bvchain[d] + acc * bvw[d];
    for (int off = 32; off >= 1; off >>= 1) p += __shfl_xor(p, off);
    if ((d & 63) == 0) red[d >> 6] = p;
    __syncthreads();
    if (d == 0) bz[a] = red[0] + red[1] + red[2] + red[3];
    return;
  }
  char* As = smem;                 // 128x64 bf16, swizzled
  char* Bs = smem + 16384;         // 256x64 bf16, swizzled
  const int lane = tid & 63, wid = tid >> 6;
  const int wr = wid >> 1, wc = wid & 1;
  const int ro = lane & 15, hi = lane >> 4;
  const int m0 = blockIdx.x * 128;

  f32x4 acc[4][8];
#pragma unroll
  for (int m = 0; m < 4; m++)
#pragma unroll
    for (int n = 0; n < 8; n++) acc[m][n] = (f32x4){0.f, 0.f, 0.f, 0.f};

  for (int k0 = 0; k0 < 128; k0 += 64) {
    // stage A (fp32 -> bf16 convert), swizzled store
#pragma unroll
    for (int it = 0; it < 4; it++) {
      const int e = (tid + it * 256) * 8;
      const int r = e >> 6, c = e & 63;
      const float* s = obs + (size_t)(m0 + r) * 128 + k0 + c;
      f32x4 a = *(const f32x4*)s, b = *(const f32x4*)(s + 4);
      U8 pk;
#pragma unroll
      for (int j = 0; j < 4; j++) { pk.u[j] = f2bf(a[j]); pk.u[4 + j] = f2bf(b[j]); }
      *(short8*)(As + ((r * 128 + c * 2) ^ ((r & 7) << 4))) = pk.v;
    }
    // stage B via cp16: linear dest, pre-swizzled global src
#pragma unroll
    for (int i = 0; i < 8; i++) {
      const int boff = i * 4096 + wid * 1024;
      const int t = boff + lane * 16;
      const int row = t >> 7;
      const int cb = (t & 127) ^ ((row & 7) << 4);
      cp16(W1b + (size_t)row * 128 + k0 + (cb >> 1), Bs + boff);
    }
    __syncthreads();
#pragma unroll
    for (int kk = 0; kk < 64; kk += 32) {
      short8 af[4], bfr[8];
#pragma unroll
      for (int m = 0; m < 4; m++) {
        const int row = wr * 64 + m * 16 + ro;
        af[m] = *(const short8*)(As + ((row * 128 + (kk + hi * 8) * 2) ^ ((row & 7) << 4)));
      }
#pragma unroll
      for (int n = 0; n < 8; n++) {
        const int row = wc * 128 + n * 16 + ro;
        bfr[n] = *(const short8*)(Bs + ((row * 128 + (kk + hi * 8) * 2) ^ ((row & 7) << 4)));
      }
#pragma unroll
      for (int m = 0; m < 4; m++)
#pragma unroll
        for (int n = 0; n < 8; n++)
          acc[m][n] = MFMA16(af[m], bfr[n], acc[m][n], 0, 0, 0);
    }
    __syncthreads();
  }

  u16 (*Cs)[264] = (u16(*)[264])smem;
#pragma unroll
  for (int half = 0; half < 2; half++) {
    if (wr == half) {
#pragma unroll
      for (int n = 0; n < 8; n++) {
        const int col = wc * 128 + n * 16 + ro;
        const float bb = b1[col];
#pragma unroll
        for (int m = 0; m < 4; m++)
#pragma unroll
          for (int j = 0; j < 4; j++)
            Cs[m * 16 + hi * 4 + j][col] = f2bf(fmaxf(acc[m][n][j] + bb, 0.f));
      }
    }
    __syncthreads();
    for (int i = tid; i < 64 * 32; i += 256) {
      const int r = i >> 5, c = (i & 31) << 3;
      *(short8*)(x1 + (size_t)(m0 + half * 64 + r) * 256 + c) = *(short8*)&Cs[r][c];
    }
    __syncthreads();
  }
}

// ---------------------------------------------------------------------------
// gemm128: C[tile 128x128] = act(A[M,256] @ W[256,256]^T + bias), swizzled LDS.
// 4 waves 2x2, acc[4][4]. smem needs 32KB.
// ---------------------------------------------------------------------------
__device__ __forceinline__ void gemm128(
    const u16* __restrict__ A, const u16* __restrict__ W,
    const float* __restrict__ bias, u16* __restrict__ C,
    const int m0, const int n0, const bool relu, char* smem) {
  char* As = smem;                 // 128x64 bf16, swizzled
  char* Bs = smem + 16384;         // 128x64 bf16, swizzled
  const int tid = threadIdx.x;
  const int lane = tid & 63, wid = tid >> 6;
  const int wr = wid >> 1, wc = wid & 1;
  const int ro = lane & 15, hi = lane >> 4;

  f32x4 acc[4][4];
#pragma unroll
  for (int m = 0; m < 4; m++)
#pragma unroll
    for (int n = 0; n < 4; n++) acc[m][n] = (f32x4){0.f, 0.f, 0.f, 0.f};

  for (int k0 = 0; k0 < 256; k0 += 64) {
#pragma unroll
    for (int i = 0; i < 4; i++) {
      const int boff = i * 4096 + wid * 1024;
      const int t = boff + lane * 16;
      const int row = t >> 7;
      const int cb = (t & 127) ^ ((row & 7) << 4);
      cp16(A + (size_t)(m0 + row) * 256 + k0 + (cb >> 1), As + boff);
    }
#pragma unroll
    for (int i = 0; i < 4; i++) {
      const int boff = i * 4096 + wid * 1024;
      const int t = boff + lane * 16;
      const int row = t >> 7;
      const int cb = (t & 127) ^ ((row & 7) << 4);
      cp16(W + (size_t)(n0 + row) * 256 + k0 + (cb >> 1), Bs + boff);
    }
    __syncthreads();
#pragma unroll
    for (int kk = 0; kk < 64; kk += 32) {
      short8 af[4], bfr[4];
#pragma unroll
      for (int m = 0; m < 4; m++) {
        const int row = wr * 64 + m * 16 + ro;
        af[m] = *(const short8*)(As + ((row * 128 + (kk + hi * 8) * 2) ^ ((row & 7) << 4)));
      }
#pragma unroll
      for (int n = 0; n < 4; n++) {
        const int row = wc * 64 + n * 16 + ro;
        bfr[n] = *(const short8*)(Bs + ((row * 128 + (kk + hi * 8) * 2) ^ ((row & 7) << 4)));
      }
#pragma unroll
      for (int m = 0; m < 4; m++)
#pragma unroll
        for (int n = 0; n < 4; n++)
          acc[m][n] = MFMA16(af[m], bfr[n], acc[m][n], 0, 0, 0);
    }
    __syncthreads();
  }

  // epilogue via LDS for coalesced stores
  u16 (*Cs)[136] = (u16(*)[136])smem;   // 64 x 136 u16 = 17.4 KB
#pragma unroll
  for (int half = 0; half < 2; half++) {
    if (wr == half) {
#pragma unroll
      for (int n = 0; n < 4; n++) {
        const int col = wc * 64 + n * 16 + ro;
        const float bb = bias[n0 + col];
#pragma unroll
        for (int m = 0; m < 4; m++)
#pragma unroll
          for (int j = 0; j < 4; j++) {
            float val = acc[m][n][j] + bb;
            if (relu) val = fmaxf(val, 0.f);
            Cs[m * 16 + hi * 4 + j][col] = f2bf(val);
          }
      }
    }
    __syncthreads();
    for (int i = tid; i < 64 * 16; i += 256) {
      const int r = i >> 4, c = (i & 15) << 3;
      *(short8*)(C + (size_t)(m0 + half * 64 + r) * 256 + n0 + c) = *(short8*)&Cs[r][c];
    }
    __syncthreads();
  }
}

// ---------------------------------------------------------------------------
// L3: x2 = relu(x1@W2^T+b2) (blocks 0..1023, 128x128 tiles) +
//     prep3 (blocks 1024..1087: G[h*16+a][:] = Wzf[a][64h:]@Wv[64h:,:])
// ---------------------------------------------------------------------------
__global__ __launch_bounds__(256, 4) void k_x2_prep3(
    const u16* __restrict__ x1, const u16* __restrict__ W2b,
    const float* __restrict__ b2, u16* __restrict__ x2,
    const float* __restrict__ Wzf, const float* __restrict__ Wv,
    u16* __restrict__ G) {
  __shared__ char smem[32768];
  if (blockIdx.x < 1024) {
    gemm128(x1, W2b, b2, x2, (blockIdx.x >> 1) * 128, (blockIdx.x & 1) * 128,
            true, smem);
    return;
  }
  const int g = blockIdx.x - 1024, d2 = threadIdx.x;
  const int h = g >> 4, a = g & 15;
  float* wzr = (float*)smem;
  if (d2 < 64) wzr[d2] = Wzf[a * 256 + h * 64 + d2];
  __syncthreads();
  float acc = 0.f;
#pragma unroll 8
  for (int d = 0; d < 64; d++) acc += wzr[d] * Wv[(size_t)(h * 64 + d) * 256 + d2];
  G[g * 256 + d2] = f2bf(acc);
}

// ---------------------------------------------------------------------------
// L4: Q/K projections (blocks 0..2047, 128x128 tiles, Q/K interleaved) +
//     gemmv (blocks 2048..2559: Vz = x2@G^T stored transposed per b)
// ---------------------------------------------------------------------------
__global__ __launch_bounds__(256, 4) void k_qk_gemmv(
    const u16* __restrict__ x2,
    const u16* __restrict__ Wqb, const float* __restrict__ bq, u16* __restrict__ Qg,
    const u16* __restrict__ Wkb, const float* __restrict__ bk, u16* __restrict__ Kg,
    const u16* __restrict__ G, u16* __restrict__ Vzt) {
  __shared__ char smem[32768];
  const int bid = blockIdx.x;
  if (bid < 2048) {
    const int which = bid & 1;
    gemm128(x2, which ? Wkb : Wqb, which ? bk : bq, which ? Kg : Qg,
            (bid >> 2) * 128, ((bid >> 1) & 1) * 128, false, smem);
    return;
  }
  // ---- gemmv: Vzraw[M,64] = x2 @ G[64,256]^T, transposed store ----
  char* As = smem;                 // 128x64 bf16, swizzled
  char* Bs = smem + 16384;         // 64x64 bf16 per K-step, swizzled
  const int tid = threadIdx.x;
  const int lane = tid & 63, w = tid >> 6;
  const int ro = lane & 15, hi = lane >> 4;
  const int m0 = (bid - 2048) * 128;

  f32x4 acc[2][4];
#pragma unroll
  for (int m = 0; m < 2; m++)
#pragma unroll
    for (int n = 0; n < 4; n++) acc[m][n] = (f32x4){0.f, 0.f, 0.f, 0.f};

  for (int k0 = 0; k0 < 256; k0 += 64) {
#pragma unroll
    for (int i = 0; i < 4; i++) {
      const int boff = i * 4096 + w * 1024;
      const int t = boff + lane * 16;
      const int row = t >> 7;
      const int cb = (t & 127) ^ ((row & 7) << 4);
      cp16(x2 + (size_t)(m0 + row) * 256 + k0 + (cb >> 1), As + boff);
    }
    {
      const int boff = w * 1024;       // 4 waves x 1KB = 4KB... 64x64 tile = 8KB: 2 issues
      const int t = boff + lane * 16;
      const int row = t >> 7;
      const int cb = (t & 127) ^ ((row & 7) << 4);
      cp16(G + (size_t)row * 256 + k0 + (cb >> 1), Bs + boff);
      const int boff2 = 4096 + w * 1024;
      const int t2 = boff2 + lane * 16;
      const int row2 = t2 >> 7;
      const int cb2 = (t2 & 127) ^ ((row2 & 7) << 4);
      cp16(G + (size_t)row2 * 256 + k0 + (cb2 >> 1), Bs + boff2);
    }
    __syncthreads();
#pragma unroll
    for (int kk = 0; kk < 64; kk += 32) {
      short8 af[2], bfr[4];
#pragma unroll
      for (int m = 0; m < 2; m++) {
        const int row = w * 32 + m * 16 + ro;
        af[m] = *(const short8*)(As + ((row * 128 + (kk + hi * 8) * 2) ^ ((row & 7) << 4)));
      }
#pragma unroll
      for (int n = 0; n < 4; n++) {
        const int row = n * 16 + ro;
        bfr[n] = *(const short8*)(Bs + ((row * 128 + (kk + hi * 8) * 2) ^ ((row & 7) << 4)));
      }
#pragma unroll
      for (int m = 0; m < 2; m++)
#pragma unroll
        for (int n = 0; n < 4; n++)
          acc[m][n] = MFMA16(af[m], bfr[n], acc[m][n], 0, 0, 0);
    }
    __syncthreads();
  }

  // transposed store: Vzt[b][c][k], 4 consecutive k per u64
#pragma unroll
  for (int m = 0; m < 2; m++) {
    const int rbase = w * 32 + m * 16;
    const int bidx = (m0 >> 6) + (rbase >> 6);
    const int ke = (rbase + hi * 4) & 63;
#pragma unroll
    for (int n = 0; n < 4; n++) {
      const int c = n * 16 + ro;
      U4 pk;
#pragma unroll
      for (int j = 0; j < 4; j++) pk.u[j] = f2bf(acc[m][n][j]);
      *(u64*)(Vzt + (size_t)bidx * 4096 + (size_t)c * 64 + ke) = pk.v;
    }
  }
}

// ---------------------------------------------------------------------------
// attn_fused: per b. QK^T -> masked in-register softmax -> P@Vz ->
// cross-head Z reduce -> out = adj@Z + b3 + deg*bz.  (unchanged from R5)
// ---------------------------------------------------------------------------
__global__ __launch_bounds__(256, 2) void attn_fused(
    const u16* __restrict__ Qg, const u16* __restrict__ Kg,
    const u16* __restrict__ Vzt, const float* __restrict__ adj,
    const float* __restrict__ bz, const float* __restrict__ b3,
    float* __restrict__ out) {
  __shared__ u16 Ps[4][64][72];
  __shared__ float Zs[4][64][16];
  __shared__ u64 adjm[64];
  __shared__ u16 chunk[64][4];

  const int b = blockIdx.x, tid = threadIdx.x;
  const int lane = tid & 63, w = tid >> 6;
  const int ro = lane & 15, hi = lane >> 4;
  const int hc = w * 64;
  const size_t base = (size_t)b * 64 * 256;

  short8 kb[4][2];
#pragma unroll
  for (int n = 0; n < 4; n++)
#pragma unroll
    for (int ks = 0; ks < 2; ks++)
      kb[n][ks] = *(const short8*)(Kg + base + (size_t)(n * 16 + ro) * 256 + hc + ks * 32 + hi * 8);

  {
    const int q = tid >> 2, qa = tid & 3;
    const float* ar = adj + ((size_t)b * 64 + q) * 64 + qa * 16;
    f32x4 a0 = *(const f32x4*)(ar);
    f32x4 a1 = *(const f32x4*)(ar + 4);
    f32x4 a2 = *(const f32x4*)(ar + 8);
    f32x4 a3 = *(const f32x4*)(ar + 12);
    unsigned m16 = 0;
#pragma unroll
    for (int i = 0; i < 4; i++) {
      m16 |= (unsigned)(a0[i] != 0.f) << i;
      m16 |= (unsigned)(a1[i] != 0.f) << (4 + i);
      m16 |= (unsigned)(a2[i] != 0.f) << (8 + i);
      m16 |= (unsigned)(a3[i] != 0.f) << (12 + i);
    }
    chunk[q][qa] = (u16)m16;
  }

  f32x4 s[4][4];
#pragma unroll
  for (int m = 0; m < 4; m++) {
    short8 af[2];
#pragma unroll
    for (int ks = 0; ks < 2; ks++)
      af[ks] = *(const short8*)(Qg + base + (size_t)(m * 16 + ro) * 256 + hc + ks * 32 + hi * 8);
#pragma unroll
    for (int n = 0; n < 4; n++) s[m][n] = (f32x4){0.f, 0.f, 0.f, 0.f};
#pragma unroll
    for (int ks = 0; ks < 2; ks++)
#pragma unroll
      for (int n = 0; n < 4; n++)
        s[m][n] = MFMA16(af[ks], kb[n][ks], s[m][n], 0, 0, 0);
  }

  short8 vz[2];
#pragma unroll
  for (int ks = 0; ks < 2; ks++)
    vz[ks] = *(const short8*)(Vzt + (size_t)b * 4096 + (size_t)(hc / 4 + ro) * 64 + ks * 32 + hi * 8);

  __syncthreads();
  if (tid < 64)
    adjm[tid] = (u64)chunk[tid][0] | ((u64)chunk[tid][1] << 16) |
                ((u64)chunk[tid][2] << 32) | ((u64)chunk[tid][3] << 48);
  __syncthreads();

#pragma unroll
  for (int m = 0; m < 4; m++) {
#pragma unroll
    for (int j = 0; j < 4; j++) {
      const int q = m * 16 + hi * 4 + j;
      const u64 msk = adjm[q];
      float sv[4], ev[4];
      float mx = -3.0e38f;
#pragma unroll
      for (int n = 0; n < 4; n++) {
        const bool on = (msk >> (n * 16 + ro)) & 1ull;
        sv[n] = on ? s[m][n][j] * 0.125f : -3.0e38f;
        mx = fmaxf(mx, sv[n]);
      }
      mx = fmaxf(mx, __shfl_xor(mx, 1));
      mx = fmaxf(mx, __shfl_xor(mx, 2));
      mx = fmaxf(mx, __shfl_xor(mx, 4));
      mx = fmaxf(mx, __shfl_xor(mx, 8));
      float sum = 0.f;
#pragma unroll
      for (int n = 0; n < 4; n++) {
        ev[n] = (sv[n] > -1.0e37f) ? __expf(sv[n] - mx) : 0.f;
        sum += ev[n];
      }
      sum += __shfl_xor(sum, 1);
      sum += __shfl_xor(sum, 2);
      sum += __shfl_xor(sum, 4);
      sum += __shfl_xor(sum, 8);
      const float inv = 1.0f / sum;
#pragma unroll
      for (int n = 0; n < 4; n++)
        Ps[w][q][n * 16 + ro] = f2bf(ev[n] * inv);
    }
  }

#pragma unroll
  for (int m = 0; m < 4; m++) {
    short8 pa[2];
    pa[0] = *(const short8*)&Ps[w][m * 16 + ro][hi * 8];
    pa[1] = *(const short8*)&Ps[w][m * 16 + ro][32 + hi * 8];
    f32x4 oz = (f32x4){0.f, 0.f, 0.f, 0.f};
#pragma unroll
    for (int ks = 0; ks < 2; ks++)
      oz = MFMA16(pa[ks], vz[ks], oz, 0, 0, 0);
#pragma unroll
    for (int j = 0; j < 4; j++)
      Zs[w][m * 16 + hi * 4 + j][ro] = oz[j];
  }
  __syncthreads();

  for (int i = tid; i < 1024; i += 256) {
    const int r = i >> 4, a = i & 15;
    Zs[0][r][a] += Zs[1][r][a] + Zs[2][r][a] + Zs[3][r][a];
  }
  __syncthreads();

  {
    const int n = tid >> 2, a4 = (tid & 3) << 2;
    const u64 msk = adjm[n];
    const float deg = (float)__popcll(msk);
    float a0 = 0.f, a1 = 0.f, a2 = 0.f, a3 = 0.f;
#pragma unroll 8
    for (int m = 0; m < 64; m++) {
      const float wv = (float)((msk >> m) & 1ull);
      f32x4 z = *(const f32x4*)&Zs[0][m][a4];
      a0 += wv * z[0]; a1 += wv * z[1]; a2 += wv * z[2]; a3 += wv * z[3];
    }
    f32x4 r;
    r[0] = a0 + b3[a4 + 0] + deg * bz[a4 + 0];
    r[1] = a1 + b3[a4 + 1] + deg * bz[a4 + 1];
    r[2] = a2 + b3[a4 + 2] + deg * bz[a4 + 2];
    r[3] = a3 + b3[a4 + 3] + deg * bz[a4 + 3];
    *(f32x4*)(out + ((size_t)b * 64 + n) * 16 + a4) = r;
  }
}

// ---------------------------------------------------------------------------
extern "C" void kernel_launch(void* const* d_in, const int* in_sizes, int n_in,
                              void* d_out, int out_size, void* d_ws, size_t ws_size,
                              hipStream_t stream) {
  const float* obs = (const float*)d_in[0];
  const float* adj = (const float*)d_in[1];
  const float* W1  = (const float*)d_in[2];
  const float* b1  = (const float*)d_in[3];
  const float* W2  = (const float*)d_in[4];
  const float* b2  = (const float*)d_in[5];
  const float* Wq  = (const float*)d_in[6];
  const float* bq  = (const float*)d_in[7];
  const float* Wk  = (const float*)d_in[8];
  const float* bk  = (const float*)d_in[9];
  const float* Wv  = (const float*)d_in[10];
  const float* bvw = (const float*)d_in[11];
  const float* Wo  = (const float*)d_in[12];
  const float* bo  = (const float*)d_in[13];
  const float* Wc  = (const float*)d_in[14];
  const float* bc  = (const float*)d_in[15];
  const float* W3  = (const float*)d_in[16];
  const float* b3  = (const float*)d_in[17];
  float* out = (float*)d_out;

  char* ws = (char*)d_ws;
  const size_t BIG = (size_t)MTOT * 256 * 2;       // 33.5 MB
  u16* buf0 = (u16*)(ws);                          // x1, then Vzt (x1 dead)
  u16* buf1 = (u16*)(ws + BIG);                    // x2
  u16* buf2 = (u16*)(ws + 2 * BIG);                // Q
  u16* buf3 = (u16*)(ws + 3 * BIG);                // K
  char* p = ws + 4 * BIG;
  u16* W1b = (u16*)p;              p += 128 * 256 * 2;
  u16* W2b = (u16*)p;              p += 256 * 256 * 2;
  u16* Wqb = (u16*)p;              p += 256 * 256 * 2;
  u16* Wkb = (u16*)p;              p += 256 * 256 * 2;
  float* M1 = (float*)p;           p += 256 * 256 * 4;
  float* Wzf = (float*)p;          p += 16 * 256 * 4;
  u16* G   = (u16*)p;              p += 64 * 256 * 2;
  float* bv = (float*)p;           p += 256 * 4;
  float* bz = (float*)p;           p += 16 * 4;

  dim3 blk(256);
  k_prep1_wconv<<<dim3(368), blk, 0, stream>>>(Wc, Wo, bo, bc, M1, bv,
                                               W1, W2, Wq, Wk, W1b, W2b, Wqb, Wkb);
  k_gemm1_prep2<<<dim3(528), blk, 0, stream>>>(obs, W1b, b1, buf0,
                                               W3, M1, bv, bvw, Wzf, bz);
  k_x2_prep3<<<dim3(1088), blk, 0, stream>>>(buf0, W2b, b2, buf1, Wzf, Wv, G);
  k_qk_gemmv<<<dim3(2560), blk, 0, stream>>>(buf1, Wqb, bq, buf2,
                                             Wkb, bk, buf3, G, buf0);
  attn_fused<<<dim3(1024), blk, 0, stream>>>(buf2, buf3, buf0, adj, bz, b3, out);
}

// Round 7
// 128.439 us; speedup vs baseline: 1.2050x; 1.2050x over previous
//
#include <hip/hip_runtime.h>
#include <stdint.h>

typedef unsigned short u16;
typedef unsigned long long u64;
typedef __attribute__((ext_vector_type(8))) short short8;
typedef __attribute__((ext_vector_type(4))) float f32x4;

#define MFMA16 __builtin_amdgcn_mfma_f32_16x16x32_bf16

#define B_ 1024
#define N_ 64
#define MTOT (B_ * N_)   // 65536

__device__ __forceinline__ u16 f2bf(float f) {
  union { float f; uint32_t u; } v; v.f = f;
  uint32_t r = v.u + 0x7FFFu + ((v.u >> 16) & 1u);
  return (u16)(r >> 16);
}

union U8 { short8 v; u16 u[8]; };
union U4 { u64 v; u16 u[4]; };

__device__ __forceinline__ void cp16(const void* g, void* l) {
  __builtin_amdgcn_global_load_lds(
      (const __attribute__((address_space(1))) void*)g,
      (__attribute__((address_space(3))) void*)l, 16, 0, 0);
}

// ---------------------------------------------------------------------------
// L1: obs fp32->bf16 (blocks 0..4095) + prep1 (4096..4351) + wconv (4352..4463)
// ---------------------------------------------------------------------------
__global__ __launch_bounds__(256) void k_l1(
    const float* __restrict__ obs, u16* __restrict__ obsb,
    const float* __restrict__ Wc, const float* __restrict__ Wo,
    const float* __restrict__ bo, const float* __restrict__ bc,
    float* __restrict__ M1, float* __restrict__ bv,
    const float* __restrict__ W1, const float* __restrict__ W2,
    const float* __restrict__ Wq, const float* __restrict__ Wk,
    u16* o1, u16* o2, u16* oq, u16* ok) {
  const int bid = blockIdx.x, tid = threadIdx.x;
  if (bid < 4096) {
    const int e = (bid * 256 + tid) * 8;
    f32x4 a = *(const f32x4*)(obs + e);
    f32x4 b = *(const f32x4*)(obs + e + 4);
    U8 pk;
#pragma unroll
    for (int j = 0; j < 4; j++) { pk.u[j] = f2bf(a[j]); pk.u[4 + j] = f2bf(b[j]); }
    *(short8*)(obsb + e) = pk.v;
  } else if (bid < 4352) {
    __shared__ float wcr[256];
    __shared__ float red[4];
    const int j = bid - 4096, d = tid;
    wcr[d] = Wc[j * 256 + d];
    __syncthreads();
    float acc = 0.f;
    for (int i = 0; i < 256; i++) acc += wcr[i] * Wo[i * 256 + d];
    M1[j * 256 + d] = acc;
    float p = wcr[d] * bo[d];
    for (int off = 32; off >= 1; off >>= 1) p += __shfl_xor(p, off);
    if ((d & 63) == 0) red[d >> 6] = p;
    __syncthreads();
    if (d == 0) bv[j] = bc[j] + red[0] + red[1] + red[2] + red[3];
  } else {
    int off8 = (bid - 4352) * 256 + tid;
    const float* src; u16* dst;
    if      (off8 <  4096) { src = W1; dst = o1; }
    else if (off8 < 12288) { src = W2; dst = o2; off8 -= 4096; }
    else if (off8 < 20480) { src = Wq; dst = oq; off8 -= 12288; }
    else                   { src = Wk; dst = ok; off8 -= 20480; }
    const int e = off8 * 8;
    f32x4 a = *(const f32x4*)(src + e);
    f32x4 b = *(const f32x4*)(src + e + 4);
    U8 pk;
#pragma unroll
    for (int j = 0; j < 4; j++) { pk.u[j] = f2bf(a[j]); pk.u[4 + j] = f2bf(b[j]); }
    *(short8*)(dst + e) = pk.v;
  }
}

// ---------------------------------------------------------------------------
// gemm128t<K>: C[m0:+128, n0:+128] = act(A[M,K] @ W[256,K]^T + bias) -> bf16.
// 4 waves 2x2, acc[4][4] (64 acc regs). XOR-swizzled LDS (both-sides, rule 21).
// smem: 32 KB.
// ---------------------------------------------------------------------------
template<int K>
__device__ __forceinline__ void gemm128t(
    const u16* __restrict__ A, const u16* __restrict__ W,
    const float* __restrict__ bias, u16* __restrict__ C,
    const int m0, const int n0, const bool relu, char* smem) {
  char* As = smem;                 // 128x64 bf16, swizzled
  char* Bs = smem + 16384;         // 128x64 bf16, swizzled
  const int tid = threadIdx.x;
  const int lane = tid & 63, wid = tid >> 6;
  const int wr = wid >> 1, wc = wid & 1;
  const int ro = lane & 15, hi = lane >> 4;

  f32x4 acc[4][4];
#pragma unroll
  for (int m = 0; m < 4; m++)
#pragma unroll
    for (int n = 0; n < 4; n++) acc[m][n] = (f32x4){0.f, 0.f, 0.f, 0.f};

  for (int k0 = 0; k0 < K; k0 += 64) {
#pragma unroll
    for (int i = 0; i < 4; i++) {
      const int boff = i * 4096 + wid * 1024;
      const int t = boff + lane * 16;
      const int row = t >> 7;
      const int cb = (t & 127) ^ ((row & 7) << 4);
      cp16(A + (size_t)(m0 + row) * K + k0 + (cb >> 1), As + boff);
    }
#pragma unroll
    for (int i = 0; i < 4; i++) {
      const int boff = i * 4096 + wid * 1024;
      const int t = boff + lane * 16;
      const int row = t >> 7;
      const int cb = (t & 127) ^ ((row & 7) << 4);
      cp16(W + (size_t)(n0 + row) * K + k0 + (cb >> 1), Bs + boff);
    }
    __syncthreads();
#pragma unroll
    for (int kk = 0; kk < 64; kk += 32) {
      short8 af[4], bfr[4];
#pragma unroll
      for (int m = 0; m < 4; m++) {
        const int row = wr * 64 + m * 16 + ro;
        af[m] = *(const short8*)(As + ((row * 128 + (kk + hi * 8) * 2) ^ ((row & 7) << 4)));
      }
#pragma unroll
      for (int n = 0; n < 4; n++) {
        const int row = wc * 64 + n * 16 + ro;
        bfr[n] = *(const short8*)(Bs + ((row * 128 + (kk + hi * 8) * 2) ^ ((row & 7) << 4)));
      }
#pragma unroll
      for (int m = 0; m < 4; m++)
#pragma unroll
        for (int n = 0; n < 4; n++)
          acc[m][n] = MFMA16(af[m], bfr[n], acc[m][n], 0, 0, 0);
    }
    __syncthreads();
  }

  u16 (*Cs)[136] = (u16(*)[136])smem;   // 64 x 136 u16 = 17.4 KB
#pragma unroll
  for (int half = 0; half < 2; half++) {
    if (wr == half) {
#pragma unroll
      for (int n = 0; n < 4; n++) {
        const int col = wc * 64 + n * 16 + ro;
        const float bb = bias[n0 + col];
#pragma unroll
        for (int m = 0; m < 4; m++)
#pragma unroll
          for (int j = 0; j < 4; j++) {
            float val = acc[m][n][j] + bb;
            if (relu) val = fmaxf(val, 0.f);
            Cs[m * 16 + hi * 4 + j][col] = f2bf(val);
          }
      }
    }
    __syncthreads();
    for (int i = tid; i < 64 * 16; i += 256) {
      const int r = i >> 4, c = (i & 15) << 3;
      *(short8*)(C + (size_t)(m0 + half * 64 + r) * 256 + n0 + c) = *(short8*)&Cs[r][c];
    }
    __syncthreads();
  }
}

// ---------------------------------------------------------------------------
// L2: gemm1 x1 = relu(obsb@W1^T+b1) (blocks 0..1023, 128x128 tiles, K=128) +
//     prep2 (blocks 1024..1039)
// ---------------------------------------------------------------------------
__global__ __launch_bounds__(256, 4) void k_gemm1_prep2(
    const u16* __restrict__ obsb, const u16* __restrict__ W1b,
    const float* __restrict__ b1, u16* __restrict__ x1,
    const float* __restrict__ W3, const float* __restrict__ M1,
    const float* __restrict__ bvchain, const float* __restrict__ bvw,
    float* __restrict__ Wzf, float* __restrict__ bz) {
  __shared__ char smem[32768];
  if (blockIdx.x < 1024) {
    gemm128t<128>(obsb, W1b, b1, x1, (int)(blockIdx.x >> 1) * 128,
                  (int)(blockIdx.x & 1) * 128, true, smem);
    return;
  }
  float* w3r = (float*)smem;
  float* red = (float*)(smem + 1024);
  const int a = blockIdx.x - 1024, d = threadIdx.x;
  w3r[d] = W3[a * 256 + d];
  __syncthreads();
  float acc = 0.f;
  for (int j = 0; j < 256; j++) acc += w3r[j] * M1[j * 256 + d];
  Wzf[a * 256 + d] = acc;
  float p = w3r[d] * bvchain[d] + acc * bvw[d];
  for (int off = 32; off >= 1; off >>= 1) p += __shfl_xor(p, off);
  if ((d & 63) == 0) red[d >> 6] = p;
  __syncthreads();
  if (d == 0) bz[a] = red[0] + red[1] + red[2] + red[3];
}

// ---------------------------------------------------------------------------
// L3: x2 = relu(x1@W2^T+b2) (blocks 0..1023) + prep3 (1024..1087)
// ---------------------------------------------------------------------------
__global__ __launch_bounds__(256, 4) void k_x2_prep3(
    const u16* __restrict__ x1, const u16* __restrict__ W2b,
    const float* __restrict__ b2, u16* __restrict__ x2,
    const float* __restrict__ Wzf, const float* __restrict__ Wv,
    u16* __restrict__ G) {
  __shared__ char smem[32768];
  if (blockIdx.x < 1024) {
    gemm128t<256>(x1, W2b, b2, x2, (int)(blockIdx.x >> 1) * 128,
                  (int)(blockIdx.x & 1) * 128, true, smem);
    return;
  }
  const int g = blockIdx.x - 1024, d2 = threadIdx.x;
  const int h = g >> 4, a = g & 15;
  float* wzr = (float*)smem;
  if (d2 < 64) wzr[d2] = Wzf[a * 256 + h * 64 + d2];
  __syncthreads();
  float acc = 0.f;
#pragma unroll 8
  for (int d = 0; d < 64; d++) acc += wzr[d] * Wv[(size_t)(h * 64 + d) * 256 + d2];
  G[g * 256 + d2] = f2bf(acc);
}

// ---------------------------------------------------------------------------
// L4: Q/K projections (blocks 0..2047) + gemmv (2048..2559)
// ---------------------------------------------------------------------------
__global__ __launch_bounds__(256, 4) void k_qk_gemmv(
    const u16* __restrict__ x2,
    const u16* __restrict__ Wqb, const float* __restrict__ bq, u16* __restrict__ Qg,
    const u16* __restrict__ Wkb, const float* __restrict__ bk, u16* __restrict__ Kg,
    const u16* __restrict__ G, u16* __restrict__ Vzt) {
  __shared__ char smem[32768];
  const int bid = blockIdx.x;
  if (bid < 2048) {
    const int which = bid & 1;
    gemm128t<256>(x2, which ? Wkb : Wqb, which ? bk : bq, which ? Kg : Qg,
                  (bid >> 2) * 128, ((bid >> 1) & 1) * 128, false, smem);
    return;
  }
  // ---- gemmv: Vzraw[M,64] = x2 @ G[64,256]^T, transposed store ----
  char* As = smem;
  char* Bs = smem + 16384;
  const int tid = threadIdx.x;
  const int lane = tid & 63, w = tid >> 6;
  const int ro = lane & 15, hi = lane >> 4;
  const int m0 = (bid - 2048) * 128;

  f32x4 acc[2][4];
#pragma unroll
  for (int m = 0; m < 2; m++)
#pragma unroll
    for (int n = 0; n < 4; n++) acc[m][n] = (f32x4){0.f, 0.f, 0.f, 0.f};

  for (int k0 = 0; k0 < 256; k0 += 64) {
#pragma unroll
    for (int i = 0; i < 4; i++) {
      const int boff = i * 4096 + w * 1024;
      const int t = boff + lane * 16;
      const int row = t >> 7;
      const int cb = (t & 127) ^ ((row & 7) << 4);
      cp16(x2 + (size_t)(m0 + row) * 256 + k0 + (cb >> 1), As + boff);
    }
    {
      const int boff = w * 1024;
      const int t = boff + lane * 16;
      const int row = t >> 7;
      const int cb = (t & 127) ^ ((row & 7) << 4);
      cp16(G + (size_t)row * 256 + k0 + (cb >> 1), Bs + boff);
      const int boff2 = 4096 + w * 1024;
      const int t2 = boff2 + lane * 16;
      const int row2 = t2 >> 7;
      const int cb2 = (t2 & 127) ^ ((row2 & 7) << 4);
      cp16(G + (size_t)row2 * 256 + k0 + (cb2 >> 1), Bs + boff2);
    }
    __syncthreads();
#pragma unroll
    for (int kk = 0; kk < 64; kk += 32) {
      short8 af[2], bfr[4];
#pragma unroll
      for (int m = 0; m < 2; m++) {
        const int row = w * 32 + m * 16 + ro;
        af[m] = *(const short8*)(As + ((row * 128 + (kk + hi * 8) * 2) ^ ((row & 7) << 4)));
      }
#pragma unroll
      for (int n = 0; n < 4; n++) {
        const int row = n * 16 + ro;
        bfr[n] = *(const short8*)(Bs + ((row * 128 + (kk + hi * 8) * 2) ^ ((row & 7) << 4)));
      }
#pragma unroll
      for (int m = 0; m < 2; m++)
#pragma unroll
        for (int n = 0; n < 4; n++)
          acc[m][n] = MFMA16(af[m], bfr[n], acc[m][n], 0, 0, 0);
    }
    __syncthreads();
  }

#pragma unroll
  for (int m = 0; m < 2; m++) {
    const int rbase = w * 32 + m * 16;
    const int bidx = (m0 >> 6) + (rbase >> 6);
    const int ke = (rbase + hi * 4) & 63;
#pragma unroll
    for (int n = 0; n < 4; n++) {
      const int c = n * 16 + ro;
      U4 pk;
#pragma unroll
      for (int j = 0; j < 4; j++) pk.u[j] = f2bf(acc[m][n][j]);
      *(u64*)(Vzt + (size_t)bidx * 4096 + (size_t)c * 64 + ke) = pk.v;
    }
  }
}

// ---------------------------------------------------------------------------
// attn_fused: per b. QK^T -> masked in-register softmax -> P@Vz ->
// cross-head Z reduce -> out = adj@Z + b3 + deg*bz.
// ---------------------------------------------------------------------------
__global__ __launch_bounds__(256, 2) void attn_fused(
    const u16* __restrict__ Qg, const u16* __restrict__ Kg,
    const u16* __restrict__ Vzt, const float* __restrict__ adj,
    const float* __restrict__ bz, const float* __restrict__ b3,
    float* __restrict__ out) {
  __shared__ u16 Ps[4][64][72];
  __shared__ float Zs[4][64][16];
  __shared__ u64 adjm[64];
  __shared__ u16 chunk[64][4];

  const int b = blockIdx.x, tid = threadIdx.x;
  const int lane = tid & 63, w = tid >> 6;
  const int ro = lane & 15, hi = lane >> 4;
  const int hc = w * 64;
  const size_t base = (size_t)b * 64 * 256;

  short8 kb[4][2];
#pragma unroll
  for (int n = 0; n < 4; n++)
#pragma unroll
    for (int ks = 0; ks < 2; ks++)
      kb[n][ks] = *(const short8*)(Kg + base + (size_t)(n * 16 + ro) * 256 + hc + ks * 32 + hi * 8);

  {
    const int q = tid >> 2, qa = tid & 3;
    const float* ar = adj + ((size_t)b * 64 + q) * 64 + qa * 16;
    f32x4 a0 = *(const f32x4*)(ar);
    f32x4 a1 = *(const f32x4*)(ar + 4);
    f32x4 a2 = *(const f32x4*)(ar + 8);
    f32x4 a3 = *(const f32x4*)(ar + 12);
    unsigned m16 = 0;
#pragma unroll
    for (int i = 0; i < 4; i++) {
      m16 |= (unsigned)(a0[i] != 0.f) << i;
      m16 |= (unsigned)(a1[i] != 0.f) << (4 + i);
      m16 |= (unsigned)(a2[i] != 0.f) << (8 + i);
      m16 |= (unsigned)(a3[i] != 0.f) << (12 + i);
    }
    chunk[q][qa] = (u16)m16;
  }

  f32x4 s[4][4];
#pragma unroll
  for (int m = 0; m < 4; m++) {
    short8 af[2];
#pragma unroll
    for (int ks = 0; ks < 2; ks++)
      af[ks] = *(const short8*)(Qg + base + (size_t)(m * 16 + ro) * 256 + hc + ks * 32 + hi * 8);
#pragma unroll
    for (int n = 0; n < 4; n++) s[m][n] = (f32x4){0.f, 0.f, 0.f, 0.f};
#pragma unroll
    for (int ks = 0; ks < 2; ks++)
#pragma unroll
      for (int n = 0; n < 4; n++)
        s[m][n] = MFMA16(af[ks], kb[n][ks], s[m][n], 0, 0, 0);
  }

  short8 vz[2];
#pragma unroll
  for (int ks = 0; ks < 2; ks++)
    vz[ks] = *(const short8*)(Vzt + (size_t)b * 4096 + (size_t)(hc / 4 + ro) * 64 + ks * 32 + hi * 8);

  __syncthreads();
  if (tid < 64)
    adjm[tid] = (u64)chunk[tid][0] | ((u64)chunk[tid][1] << 16) |
                ((u64)chunk[tid][2] << 32) | ((u64)chunk[tid][3] << 48);
  __syncthreads();

#pragma unroll
  for (int m = 0; m < 4; m++) {
#pragma unroll
    for (int j = 0; j < 4; j++) {
      const int q = m * 16 + hi * 4 + j;
      const u64 msk = adjm[q];
      float sv[4], ev[4];
      float mx = -3.0e38f;
#pragma unroll
      for (int n = 0; n < 4; n++) {
        const bool on = (msk >> (n * 16 + ro)) & 1ull;
        sv[n] = on ? s[m][n][j] * 0.125f : -3.0e38f;
        mx = fmaxf(mx, sv[n]);
      }
      mx = fmaxf(mx, __shfl_xor(mx, 1));
      mx = fmaxf(mx, __shfl_xor(mx, 2));
      mx = fmaxf(mx, __shfl_xor(mx, 4));
      mx = fmaxf(mx, __shfl_xor(mx, 8));
      float sum = 0.f;
#pragma unroll
      for (int n = 0; n < 4; n++) {
        ev[n] = (sv[n] > -1.0e37f) ? __expf(sv[n] - mx) : 0.f;
        sum += ev[n];
      }
      sum += __shfl_xor(sum, 1);
      sum += __shfl_xor(sum, 2);
      sum += __shfl_xor(sum, 4);
      sum += __shfl_xor(sum, 8);
      const float inv = 1.0f / sum;
#pragma unroll
      for (int n = 0; n < 4; n++)
        Ps[w][q][n * 16 + ro] = f2bf(ev[n] * inv);
    }
  }

#pragma unroll
  for (int m = 0; m < 4; m++) {
    short8 pa[2];
    pa[0] = *(const short8*)&Ps[w][m * 16 + ro][hi * 8];
    pa[1] = *(const short8*)&Ps[w][m * 16 + ro][32 + hi * 8];
    f32x4 oz = (f32x4){0.f, 0.f, 0.f, 0.f};
#pragma unroll
    for (int ks = 0; ks < 2; ks++)
      oz = MFMA16(pa[ks], vz[ks], oz, 0, 0, 0);
#pragma unroll
    for (int j = 0; j < 4; j++)
      Zs[w][m * 16 + hi * 4 + j][ro] = oz[j];
  }
  __syncthreads();

  for (int i = tid; i < 1024; i += 256) {
    const int r = i >> 4, a = i & 15;
    Zs[0][r][a] += Zs[1][r][a] + Zs[2][r][a] + Zs[3][r][a];
  }
  __syncthreads();

  {
    const int n = tid >> 2, a4 = (tid & 3) << 2;
    const u64 msk = adjm[n];
    const float deg = (float)__popcll(msk);
    float a0 = 0.f, a1 = 0.f, a2 = 0.f, a3 = 0.f;
#pragma unroll 8
    for (int m = 0; m < 64; m++) {
      const float wv = (float)((msk >> m) & 1ull);
      f32x4 z = *(const f32x4*)&Zs[0][m][a4];
      a0 += wv * z[0]; a1 += wv * z[1]; a2 += wv * z[2]; a3 += wv * z[3];
    }
    f32x4 r;
    r[0] = a0 + b3[a4 + 0] + deg * bz[a4 + 0];
    r[1] = a1 + b3[a4 + 1] + deg * bz[a4 + 1];
    r[2] = a2 + b3[a4 + 2] + deg * bz[a4 + 2];
    r[3] = a3 + b3[a4 + 3] + deg * bz[a4 + 3];
    *(f32x4*)(out + ((size_t)b * 64 + n) * 16 + a4) = r;
  }
}

// ---------------------------------------------------------------------------
extern "C" void kernel_launch(void* const* d_in, const int* in_sizes, int n_in,
                              void* d_out, int out_size, void* d_ws, size_t ws_size,
                              hipStream_t stream) {
  const float* obs = (const float*)d_in[0];
  const float* adj = (const float*)d_in[1];
  const float* W1  = (const float*)d_in[2];
  const float* b1  = (const float*)d_in[3];
  const float* W2  = (const float*)d_in[4];
  const float* b2  = (const float*)d_in[5];
  const float* Wq  = (const float*)d_in[6];
  const float* bq  = (const float*)d_in[7];
  const float* Wk  = (const float*)d_in[8];
  const float* bk  = (const float*)d_in[9];
  const float* Wv  = (const float*)d_in[10];
  const float* bvw = (const float*)d_in[11];
  const float* Wo  = (const float*)d_in[12];
  const float* bo  = (const float*)d_in[13];
  const float* Wc  = (const float*)d_in[14];
  const float* bc  = (const float*)d_in[15];
  const float* W3  = (const float*)d_in[16];
  const float* b3  = (const float*)d_in[17];
  float* out = (float*)d_out;

  char* ws = (char*)d_ws;
  const size_t BIG = (size_t)MTOT * 256 * 2;       // 33.5 MB
  u16* buf0 = (u16*)(ws);                          // x1, then Vzt (x1 dead)
  u16* buf1 = (u16*)(ws + BIG);                    // x2
  u16* buf2 = (u16*)(ws + 2 * BIG);                // Q
  u16* buf3 = (u16*)(ws + 3 * BIG);                // K
  char* p = ws + 4 * BIG;
  u16* W1b = (u16*)p;              p += 128 * 256 * 2;
  u16* W2b = (u16*)p;              p += 256 * 256 * 2;
  u16* Wqb = (u16*)p;              p += 256 * 256 * 2;
  u16* Wkb = (u16*)p;              p += 256 * 256 * 2;
  float* M1 = (float*)p;           p += 256 * 256 * 4;
  float* Wzf = (float*)p;          p += 16 * 256 * 4;
  u16* G   = (u16*)p;              p += 64 * 256 * 2;
  float* bv = (float*)p;           p += 256 * 4;
  float* bz = (float*)p;           p += 16 * 4;
  u16* obsb = (u16*)p;             p += (size_t)MTOT * 128 * 2;   // 16.8 MB

  dim3 blk(256);
  k_l1<<<dim3(4464), blk, 0, stream>>>(obs, obsb, Wc, Wo, bo, bc, M1, bv,
                                       W1, W2, Wq, Wk, W1b, W2b, Wqb, Wkb);
  k_gemm1_prep2<<<dim3(1040), blk, 0, stream>>>(obsb, W1b, b1, buf0,
                                                W3, M1, bv, bvw, Wzf, bz);
  k_x2_prep3<<<dim3(1088), blk, 0, stream>>>(buf0, W2b, b2, buf1, Wzf, Wv, G);
  k_qk_gemmv<<<dim3(2560), blk, 0, stream>>>(buf1, Wqb, bq, buf2,
                                             Wkb, bk, buf3, G, buf0);
  attn_fused<<<dim3(1024), blk, 0, stream>>>(buf2, buf3, buf0, adj, bz, b3, out);
}

// Round 8
// 125.241 us; speedup vs baseline: 1.2358x; 1.0255x over previous
//
#include <hip/hip_runtime.h>
#include <stdint.h>

typedef unsigned short u16;
typedef unsigned long long u64;
typedef __attribute__((ext_vector_type(8))) short short8;
typedef __attribute__((ext_vector_type(4))) float f32x4;

#define MFMA16 __builtin_amdgcn_mfma_f32_16x16x32_bf16

#define B_ 1024
#define N_ 64
#define MTOT (B_ * N_)   // 65536

__device__ __forceinline__ u16 f2bf(float f) {
  union { float f; uint32_t u; } v; v.f = f;
  uint32_t r = v.u + 0x7FFFu + ((v.u >> 16) & 1u);
  return (u16)(r >> 16);
}

union U8 { short8 v; u16 u[8]; };
union U4 { u64 v; u16 u[4]; };

__device__ __forceinline__ void cp16(const void* g, void* l) {
  __builtin_amdgcn_global_load_lds(
      (const __attribute__((address_space(1))) void*)g,
      (__attribute__((address_space(3))) void*)l, 16, 0, 0);
}

// ---------------------------------------------------------------------------
// L1: obs fp32->bf16 (blocks 0..4095) + prep1 (4096..4351) + wconv (4352..4463)
// ---------------------------------------------------------------------------
__global__ __launch_bounds__(256) void k_l1(
    const float* __restrict__ obs, u16* __restrict__ obsb,
    const float* __restrict__ Wc, const float* __restrict__ Wo,
    const float* __restrict__ bo, const float* __restrict__ bc,
    float* __restrict__ M1, float* __restrict__ bv,
    const float* __restrict__ W1, const float* __restrict__ W2,
    const float* __restrict__ Wq, const float* __restrict__ Wk,
    u16* o1, u16* o2, u16* oq, u16* ok) {
  const int bid = blockIdx.x, tid = threadIdx.x;
  if (bid < 4096) {
    const int e = (bid * 256 + tid) * 8;
    f32x4 a = *(const f32x4*)(obs + e);
    f32x4 b = *(const f32x4*)(obs + e + 4);
    U8 pk;
#pragma unroll
    for (int j = 0; j < 4; j++) { pk.u[j] = f2bf(a[j]); pk.u[4 + j] = f2bf(b[j]); }
    *(short8*)(obsb + e) = pk.v;
  } else if (bid < 4352) {
    __shared__ float wcr[256];
    __shared__ float red[4];
    const int j = bid - 4096, d = tid;
    wcr[d] = Wc[j * 256 + d];
    __syncthreads();
    float acc = 0.f;
    for (int i = 0; i < 256; i++) acc += wcr[i] * Wo[i * 256 + d];
    M1[j * 256 + d] = acc;
    float p = wcr[d] * bo[d];
    for (int off = 32; off >= 1; off >>= 1) p += __shfl_xor(p, off);
    if ((d & 63) == 0) red[d >> 6] = p;
    __syncthreads();
    if (d == 0) bv[j] = bc[j] + red[0] + red[1] + red[2] + red[3];
  } else {
    int off8 = (bid - 4352) * 256 + tid;
    const float* src; u16* dst;
    if      (off8 <  4096) { src = W1; dst = o1; }
    else if (off8 < 12288) { src = W2; dst = o2; off8 -= 4096; }
    else if (off8 < 20480) { src = Wq; dst = oq; off8 -= 12288; }
    else                   { src = Wk; dst = ok; off8 -= 20480; }
    const int e = off8 * 8;
    f32x4 a = *(const f32x4*)(src + e);
    f32x4 b = *(const f32x4*)(src + e + 4);
    U8 pk;
#pragma unroll
    for (int j = 0; j < 4; j++) { pk.u[j] = f2bf(a[j]); pk.u[4 + j] = f2bf(b[j]); }
    *(short8*)(dst + e) = pk.v;
  }
}

// ---------------------------------------------------------------------------
// gemm_full<K>: C[m0:+128, 0:256] = act(A[M,K] @ W[256,K]^T + bias) -> bf16.
// Both 128-col halves in one block: A staged ONCE per K-step, 64 MFMA/wave
// per barrier-pair. acc0+acc1 = 128 VGPRs, launch_bounds(256,2) (no spill).
// LDS: As 16K + Bs0 16K + Bs1 16K = 48 KB. XOR-swizzled (both sides, rule 21).
// ---------------------------------------------------------------------------
template<int K>
__device__ __forceinline__ void gemm_full(
    const u16* __restrict__ A, const u16* __restrict__ W,
    const float* __restrict__ bias, u16* __restrict__ C,
    const int m0, const bool relu, char* smem) {
  char* As  = smem;
  char* Bs0 = smem + 16384;
  char* Bs1 = smem + 32768;
  const int tid = threadIdx.x;
  const int lane = tid & 63, wid = tid >> 6;
  const int wr = wid >> 1, wc = wid & 1;
  const int ro = lane & 15, hi = lane >> 4;

  f32x4 acc0[4][4], acc1[4][4];
#pragma unroll
  for (int m = 0; m < 4; m++)
#pragma unroll
    for (int n = 0; n < 4; n++) {
      acc0[m][n] = (f32x4){0.f, 0.f, 0.f, 0.f};
      acc1[m][n] = (f32x4){0.f, 0.f, 0.f, 0.f};
    }

  for (int k0 = 0; k0 < K; k0 += 64) {
#pragma unroll
    for (int i = 0; i < 4; i++) {
      const int boff = i * 4096 + wid * 1024;
      const int t = boff + lane * 16;
      const int row = t >> 7;
      const int cb = (t & 127) ^ ((row & 7) << 4);
      cp16(A + (size_t)(m0 + row) * K + k0 + (cb >> 1), As + boff);
      cp16(W + (size_t)row * K + k0 + (cb >> 1), Bs0 + boff);
      cp16(W + (size_t)(128 + row) * K + k0 + (cb >> 1), Bs1 + boff);
    }
    __syncthreads();
#pragma unroll
    for (int kk = 0; kk < 64; kk += 32) {
      short8 af[4], b0[4], b1[4];
#pragma unroll
      for (int m = 0; m < 4; m++) {
        const int row = wr * 64 + m * 16 + ro;
        af[m] = *(const short8*)(As + ((row * 128 + (kk + hi * 8) * 2) ^ ((row & 7) << 4)));
      }
#pragma unroll
      for (int n = 0; n < 4; n++) {
        const int row = wc * 64 + n * 16 + ro;
        const int off = (row * 128 + (kk + hi * 8) * 2) ^ ((row & 7) << 4);
        b0[n] = *(const short8*)(Bs0 + off);
        b1[n] = *(const short8*)(Bs1 + off);
      }
#pragma unroll
      for (int m = 0; m < 4; m++)
#pragma unroll
        for (int n = 0; n < 4; n++) {
          acc0[m][n] = MFMA16(af[m], b0[n], acc0[m][n], 0, 0, 0);
          acc1[m][n] = MFMA16(af[m], b1[n], acc1[m][n], 0, 0, 0);
        }
    }
    __syncthreads();
  }

  // epilogue: per col-half, per row-half, through LDS for coalesced stores
  u16 (*Cs)[136] = (u16(*)[136])smem;
  auto ep = [&](f32x4 (&acc)[4][4], const int n0) {
#pragma unroll
    for (int half = 0; half < 2; half++) {
      if (wr == half) {
#pragma unroll
        for (int n = 0; n < 4; n++) {
          const int col = wc * 64 + n * 16 + ro;
          const float bb = bias[n0 + col];
#pragma unroll
          for (int m = 0; m < 4; m++)
#pragma unroll
            for (int j = 0; j < 4; j++) {
              float val = acc[m][n][j] + bb;
              if (relu) val = fmaxf(val, 0.f);
              Cs[m * 16 + hi * 4 + j][col] = f2bf(val);
            }
        }
      }
      __syncthreads();
      for (int i = tid; i < 64 * 16; i += 256) {
        const int r = i >> 4, c = (i & 15) << 3;
        *(short8*)(C + (size_t)(m0 + half * 64 + r) * 256 + n0 + c) = *(short8*)&Cs[r][c];
      }
      __syncthreads();
    }
  };
  ep(acc0, 0);
  ep(acc1, 128);
}

// ---------------------------------------------------------------------------
// L2: gemm1 x1 = relu(obsb@W1^T+b1) (blocks 0..511, full-row tiles, K=128) +
//     prep2 (blocks 512..527)
// ---------------------------------------------------------------------------
__global__ __launch_bounds__(256, 2) void k_gemm1_prep2(
    const u16* __restrict__ obsb, const u16* __restrict__ W1b,
    const float* __restrict__ b1, u16* __restrict__ x1,
    const float* __restrict__ W3, const float* __restrict__ M1,
    const float* __restrict__ bvchain, const float* __restrict__ bvw,
    float* __restrict__ Wzf, float* __restrict__ bz) {
  __shared__ char smem[49152];
  if (blockIdx.x < 512) {
    gemm_full<128>(obsb, W1b, b1, x1, (int)blockIdx.x * 128, true, smem);
    return;
  }
  float* w3r = (float*)smem;
  float* red = (float*)(smem + 1024);
  const int a = blockIdx.x - 512, d = threadIdx.x;
  w3r[d] = W3[a * 256 + d];
  __syncthreads();
  float acc = 0.f;
  for (int j = 0; j < 256; j++) acc += w3r[j] * M1[j * 256 + d];
  Wzf[a * 256 + d] = acc;
  float p = w3r[d] * bvchain[d] + acc * bvw[d];
  for (int off = 32; off >= 1; off >>= 1) p += __shfl_xor(p, off);
  if ((d & 63) == 0) red[d >> 6] = p;
  __syncthreads();
  if (d == 0) bz[a] = red[0] + red[1] + red[2] + red[3];
}

// ---------------------------------------------------------------------------
// L3: x2 = relu(x1@W2^T+b2) (blocks 0..511) + prep3 (512..575)
// ---------------------------------------------------------------------------
__global__ __launch_bounds__(256, 2) void k_x2_prep3(
    const u16* __restrict__ x1, const u16* __restrict__ W2b,
    const float* __restrict__ b2, u16* __restrict__ x2,
    const float* __restrict__ Wzf, const float* __restrict__ Wv,
    u16* __restrict__ G) {
  __shared__ char smem[49152];
  if (blockIdx.x < 512) {
    gemm_full<256>(x1, W2b, b2, x2, (int)blockIdx.x * 128, true, smem);
    return;
  }
  const int g = blockIdx.x - 512, d2 = threadIdx.x;
  const int h = g >> 4, a = g & 15;
  float* wzr = (float*)smem;
  if (d2 < 64) wzr[d2] = Wzf[a * 256 + h * 64 + d2];
  __syncthreads();
  float acc = 0.f;
#pragma unroll 8
  for (int d = 0; d < 64; d++) acc += wzr[d] * Wv[(size_t)(h * 64 + d) * 256 + d2];
  G[g * 256 + d2] = f2bf(acc);
}

// ---------------------------------------------------------------------------
// L4: Q (sub=0) / K (sub=1) full-row tiles (blocks 0..1023, XCD-paired so the
// Q-block and K-block of the same m-tile share an XCD L2) + gemmv (1024..1535)
// ---------------------------------------------------------------------------
__global__ __launch_bounds__(256, 2) void k_qk_gemmv(
    const u16* __restrict__ x2,
    const u16* __restrict__ Wqb, const float* __restrict__ bq, u16* __restrict__ Qg,
    const u16* __restrict__ Wkb, const float* __restrict__ bk, u16* __restrict__ Kg,
    const u16* __restrict__ G, u16* __restrict__ Vzt) {
  __shared__ char smem[49152];
  const int bid = blockIdx.x;
  if (bid < 1024) {
    // same-XCD pairing: ids q*16+r and q*16+r+8 (same id%8 -> same XCD)
    // decode to the same m-tile, sub = Q/K.
    const int q = bid >> 4, r = bid & 15;
    const int mt = q * 8 + (r & 7);
    const int sub = r >> 3;
    gemm_full<256>(x2, sub ? Wkb : Wqb, sub ? bk : bq, sub ? Kg : Qg,
                   mt * 128, false, smem);
    return;
  }
  // ---- gemmv: Vzraw[M,64] = x2 @ G[64,256]^T, transposed store ----
  char* As = smem;
  char* Bs = smem + 16384;
  const int tid = threadIdx.x;
  const int lane = tid & 63, w = tid >> 6;
  const int ro = lane & 15, hi = lane >> 4;
  const int m0 = (bid - 1024) * 128;

  f32x4 acc[2][4];
#pragma unroll
  for (int m = 0; m < 2; m++)
#pragma unroll
    for (int n = 0; n < 4; n++) acc[m][n] = (f32x4){0.f, 0.f, 0.f, 0.f};

  for (int k0 = 0; k0 < 256; k0 += 64) {
#pragma unroll
    for (int i = 0; i < 4; i++) {
      const int boff = i * 4096 + w * 1024;
      const int t = boff + lane * 16;
      const int row = t >> 7;
      const int cb = (t & 127) ^ ((row & 7) << 4);
      cp16(x2 + (size_t)(m0 + row) * 256 + k0 + (cb >> 1), As + boff);
    }
    {
      const int boff = w * 1024;
      const int t = boff + lane * 16;
      const int row = t >> 7;
      const int cb = (t & 127) ^ ((row & 7) << 4);
      cp16(G + (size_t)row * 256 + k0 + (cb >> 1), Bs + boff);
      const int boff2 = 4096 + w * 1024;
      const int t2 = boff2 + lane * 16;
      const int row2 = t2 >> 7;
      const int cb2 = (t2 & 127) ^ ((row2 & 7) << 4);
      cp16(G + (size_t)row2 * 256 + k0 + (cb2 >> 1), Bs + boff2);
    }
    __syncthreads();
#pragma unroll
    for (int kk = 0; kk < 64; kk += 32) {
      short8 af[2], bfr[4];
#pragma unroll
      for (int m = 0; m < 2; m++) {
        const int row = w * 32 + m * 16 + ro;
        af[m] = *(const short8*)(As + ((row * 128 + (kk + hi * 8) * 2) ^ ((row & 7) << 4)));
      }
#pragma unroll
      for (int n = 0; n < 4; n++) {
        const int row = n * 16 + ro;
        bfr[n] = *(const short8*)(Bs + ((row * 128 + (kk + hi * 8) * 2) ^ ((row & 7) << 4)));
      }
#pragma unroll
      for (int m = 0; m < 2; m++)
#pragma unroll
        for (int n = 0; n < 4; n++)
          acc[m][n] = MFMA16(af[m], bfr[n], acc[m][n], 0, 0, 0);
    }
    __syncthreads();
  }

#pragma unroll
  for (int m = 0; m < 2; m++) {
    const int rbase = w * 32 + m * 16;
    const int bidx = (m0 >> 6) + (rbase >> 6);
    const int ke = (rbase + hi * 4) & 63;
#pragma unroll
    for (int n = 0; n < 4; n++) {
      const int c = n * 16 + ro;
      U4 pk;
#pragma unroll
      for (int j = 0; j < 4; j++) pk.u[j] = f2bf(acc[m][n][j]);
      *(u64*)(Vzt + (size_t)bidx * 4096 + (size_t)c * 64 + ke) = pk.v;
    }
  }
}

// ---------------------------------------------------------------------------
// attn_fused: per b. QK^T -> masked in-register softmax -> P@Vz ->
// cross-head Z reduce -> out = adj@Z + b3 + deg*bz.
// ---------------------------------------------------------------------------
__global__ __launch_bounds__(256, 2) void attn_fused(
    const u16* __restrict__ Qg, const u16* __restrict__ Kg,
    const u16* __restrict__ Vzt, const float* __restrict__ adj,
    const float* __restrict__ bz, const float* __restrict__ b3,
    float* __restrict__ out) {
  __shared__ u16 Ps[4][64][72];
  __shared__ float Zs[4][64][16];
  __shared__ u64 adjm[64];
  __shared__ u16 chunk[64][4];

  const int b = blockIdx.x, tid = threadIdx.x;
  const int lane = tid & 63, w = tid >> 6;
  const int ro = lane & 15, hi = lane >> 4;
  const int hc = w * 64;
  const size_t base = (size_t)b * 64 * 256;

  short8 kb[4][2];
#pragma unroll
  for (int n = 0; n < 4; n++)
#pragma unroll
    for (int ks = 0; ks < 2; ks++)
      kb[n][ks] = *(const short8*)(Kg + base + (size_t)(n * 16 + ro) * 256 + hc + ks * 32 + hi * 8);

  {
    const int q = tid >> 2, qa = tid & 3;
    const float* ar = adj + ((size_t)b * 64 + q) * 64 + qa * 16;
    f32x4 a0 = *(const f32x4*)(ar);
    f32x4 a1 = *(const f32x4*)(ar + 4);
    f32x4 a2 = *(const f32x4*)(ar + 8);
    f32x4 a3 = *(const f32x4*)(ar + 12);
    unsigned m16 = 0;
#pragma unroll
    for (int i = 0; i < 4; i++) {
      m16 |= (unsigned)(a0[i] != 0.f) << i;
      m16 |= (unsigned)(a1[i] != 0.f) << (4 + i);
      m16 |= (unsigned)(a2[i] != 0.f) << (8 + i);
      m16 |= (unsigned)(a3[i] != 0.f) << (12 + i);
    }
    chunk[q][qa] = (u16)m16;
  }

  f32x4 s[4][4];
#pragma unroll
  for (int m = 0; m < 4; m++) {
    short8 af[2];
#pragma unroll
    for (int ks = 0; ks < 2; ks++)
      af[ks] = *(const short8*)(Qg + base + (size_t)(m * 16 + ro) * 256 + hc + ks * 32 + hi * 8);
#pragma unroll
    for (int n = 0; n < 4; n++) s[m][n] = (f32x4){0.f, 0.f, 0.f, 0.f};
#pragma unroll
    for (int ks = 0; ks < 2; ks++)
#pragma unroll
      for (int n = 0; n < 4; n++)
        s[m][n] = MFMA16(af[ks], kb[n][ks], s[m][n], 0, 0, 0);
  }

  short8 vz[2];
#pragma unroll
  for (int ks = 0; ks < 2; ks++)
    vz[ks] = *(const short8*)(Vzt + (size_t)b * 4096 + (size_t)(hc / 4 + ro) * 64 + ks * 32 + hi * 8);

  __syncthreads();
  if (tid < 64)
    adjm[tid] = (u64)chunk[tid][0] | ((u64)chunk[tid][1] << 16) |
                ((u64)chunk[tid][2] << 32) | ((u64)chunk[tid][3] << 48);
  __syncthreads();

#pragma unroll
  for (int m = 0; m < 4; m++) {
#pragma unroll
    for (int j = 0; j < 4; j++) {
      const int q = m * 16 + hi * 4 + j;
      const u64 msk = adjm[q];
      float sv[4], ev[4];
      float mx = -3.0e38f;
#pragma unroll
      for (int n = 0; n < 4; n++) {
        const bool on = (msk >> (n * 16 + ro)) & 1ull;
        sv[n] = on ? s[m][n][j] * 0.125f : -3.0e38f;
        mx = fmaxf(mx, sv[n]);
      }
      mx = fmaxf(mx, __shfl_xor(mx, 1));
      mx = fmaxf(mx, __shfl_xor(mx, 2));
      mx = fmaxf(mx, __shfl_xor(mx, 4));
      mx = fmaxf(mx, __shfl_xor(mx, 8));
      float sum = 0.f;
#pragma unroll
      for (int n = 0; n < 4; n++) {
        ev[n] = (sv[n] > -1.0e37f) ? __expf(sv[n] - mx) : 0.f;
        sum += ev[n];
      }
      sum += __shfl_xor(sum, 1);
      sum += __shfl_xor(sum, 2);
      sum += __shfl_xor(sum, 4);
      sum += __shfl_xor(sum, 8);
      const float inv = 1.0f / sum;
#pragma unroll
      for (int n = 0; n < 4; n++)
        Ps[w][q][n * 16 + ro] = f2bf(ev[n] * inv);
    }
  }

#pragma unroll
  for (int m = 0; m < 4; m++) {
    short8 pa[2];
    pa[0] = *(const short8*)&Ps[w][m * 16 + ro][hi * 8];
    pa[1] = *(const short8*)&Ps[w][m * 16 + ro][32 + hi * 8];
    f32x4 oz = (f32x4){0.f, 0.f, 0.f, 0.f};
#pragma unroll
    for (int ks = 0; ks < 2; ks++)
      oz = MFMA16(pa[ks], vz[ks], oz, 0, 0, 0);
#pragma unroll
    for (int j = 0; j < 4; j++)
      Zs[w][m * 16 + hi * 4 + j][ro] = oz[j];
  }
  __syncthreads();

  for (int i = tid; i < 1024; i += 256) {
    const int r = i >> 4, a = i & 15;
    Zs[0][r][a] += Zs[1][r][a] + Zs[2][r][a] + Zs[3][r][a];
  }
  __syncthreads();

  {
    const int n = tid >> 2, a4 = (tid & 3) << 2;
    const u64 msk = adjm[n];
    const float deg = (float)__popcll(msk);
    float a0 = 0.f, a1 = 0.f, a2 = 0.f, a3 = 0.f;
#pragma unroll 8
    for (int m = 0; m < 64; m++) {
      const float wv = (float)((msk >> m) & 1ull);
      f32x4 z = *(const f32x4*)&Zs[0][m][a4];
      a0 += wv * z[0]; a1 += wv * z[1]; a2 += wv * z[2]; a3 += wv * z[3];
    }
    f32x4 r;
    r[0] = a0 + b3[a4 + 0] + deg * bz[a4 + 0];
    r[1] = a1 + b3[a4 + 1] + deg * bz[a4 + 1];
    r[2] = a2 + b3[a4 + 2] + deg * bz[a4 + 2];
    r[3] = a3 + b3[a4 + 3] + deg * bz[a4 + 3];
    *(f32x4*)(out + ((size_t)b * 64 + n) * 16 + a4) = r;
  }
}

// ---------------------------------------------------------------------------
extern "C" void kernel_launch(void* const* d_in, const int* in_sizes, int n_in,
                              void* d_out, int out_size, void* d_ws, size_t ws_size,
                              hipStream_t stream) {
  const float* obs = (const float*)d_in[0];
  const float* adj = (const float*)d_in[1];
  const float* W1  = (const float*)d_in[2];
  const float* b1  = (const float*)d_in[3];
  const float* W2  = (const float*)d_in[4];
  const float* b2  = (const float*)d_in[5];
  const float* Wq  = (const float*)d_in[6];
  const float* bq  = (const float*)d_in[7];
  const float* Wk  = (const float*)d_in[8];
  const float* bk  = (const float*)d_in[9];
  const float* Wv  = (const float*)d_in[10];
  const float* bvw = (const float*)d_in[11];
  const float* Wo  = (const float*)d_in[12];
  const float* bo  = (const float*)d_in[13];
  const float* Wc  = (const float*)d_in[14];
  const float* bc  = (const float*)d_in[15];
  const float* W3  = (const float*)d_in[16];
  const float* b3  = (const float*)d_in[17];
  float* out = (float*)d_out;

  char* ws = (char*)d_ws;
  const size_t BIG = (size_t)MTOT * 256 * 2;       // 33.5 MB
  u16* buf0 = (u16*)(ws);                          // x1, then Vzt (x1 dead)
  u16* buf1 = (u16*)(ws + BIG);                    // x2
  u16* buf2 = (u16*)(ws + 2 * BIG);                // Q
  u16* buf3 = (u16*)(ws + 3 * BIG);                // K
  char* p = ws + 4 * BIG;
  u16* W1b = (u16*)p;              p += 128 * 256 * 2;
  u16* W2b = (u16*)p;              p += 256 * 256 * 2;
  u16* Wqb = (u16*)p;              p += 256 * 256 * 2;
  u16* Wkb = (u16*)p;              p += 256 * 256 * 2;
  float* M1 = (float*)p;           p += 256 * 256 * 4;
  float* Wzf = (float*)p;          p += 16 * 256 * 4;
  u16* G   = (u16*)p;              p += 64 * 256 * 2;
  float* bv = (float*)p;           p += 256 * 4;
  float* bz = (float*)p;           p += 16 * 4;
  u16* obsb = (u16*)p;             p += (size_t)MTOT * 128 * 2;   // 16.8 MB

  dim3 blk(256);
  k_l1<<<dim3(4464), blk, 0, stream>>>(obs, obsb, Wc, Wo, bo, bc, M1, bv,
                                       W1, W2, Wq, Wk, W1b, W2b, Wqb, Wkb);
  k_gemm1_prep2<<<dim3(528), blk, 0, stream>>>(obsb, W1b, b1, buf0,
                                               W3, M1, bv, bvw, Wzf, bz);
  k_x2_prep3<<<dim3(576), blk, 0, stream>>>(buf0, W2b, b2, buf1, Wzf, Wv, G);
  k_qk_gemmv<<<dim3(1536), blk, 0, stream>>>(buf1, Wqb, bq, buf2,
                                             Wkb, bk, buf3, G, buf0);
  attn_fused<<<dim3(1024), blk, 0, stream>>>(buf2, buf3, buf0, adj, bz, b3, out);
}

// Round 10
// 122.503 us; speedup vs baseline: 1.2634x; 1.0223x over previous
//
#include <hip/hip_runtime.h>
#include <stdint.h>

typedef unsigned short u16;
typedef unsigned long long u64;
typedef __attribute__((ext_vector_type(8))) short short8;
typedef __attribute__((ext_vector_type(4))) float f32x4;

#define MFMA16 __builtin_amdgcn_mfma_f32_16x16x32_bf16

#define MTOT 65536   // B*N = 1024*64

__device__ __forceinline__ u16 f2bf(float f) {
  union { float f; uint32_t u; } v; v.f = f;
  uint32_t r = v.u + 0x7FFFu + ((v.u >> 16) & 1u);
  return (u16)(r >> 16);
}

union U8 { short8 v; u16 u[8]; };
union U4 { u64 v; u16 u[4]; };

__device__ __forceinline__ void cp16(const void* g, void* l) {
  __builtin_amdgcn_global_load_lds(
      (const __attribute__((address_space(1))) void*)g,
      (__attribute__((address_space(3))) void*)l, 16, 0, 0);
}

// ---------------------------------------------------------------------------
// L1: prep1 (blocks 0..255) + wconv of W1,W2,Wq,Wk (blocks 256..367)
// ---------------------------------------------------------------------------
__global__ __launch_bounds__(256) void k_l1(
    const float* __restrict__ Wc, const float* __restrict__ Wo,
    const float* __restrict__ bo, const float* __restrict__ bc,
    float* __restrict__ M1, float* __restrict__ bv,
    const float* __restrict__ W1, const float* __restrict__ W2,
    const float* __restrict__ Wq, const float* __restrict__ Wk,
    u16* o1, u16* o2, u16* oq, u16* ok) {
  const int bid = blockIdx.x, tid = threadIdx.x;
  if (bid < 256) {
    __shared__ float wcr[256];
    __shared__ float red[4];
    const int j = bid, d = tid;
    wcr[d] = Wc[j * 256 + d];
    __syncthreads();
    float acc = 0.f;
    for (int i = 0; i < 256; i++) acc += wcr[i] * Wo[i * 256 + d];
    M1[j * 256 + d] = acc;
    float p = wcr[d] * bo[d];
    for (int off = 32; off >= 1; off >>= 1) p += __shfl_xor(p, off);
    if ((d & 63) == 0) red[d >> 6] = p;
    __syncthreads();
    if (d == 0) bv[j] = bc[j] + red[0] + red[1] + red[2] + red[3];
  } else {
    int off8 = (bid - 256) * 256 + tid;
    const float* src; u16* dst;
    if      (off8 <  4096) { src = W1; dst = o1; }
    else if (off8 < 12288) { src = W2; dst = o2; off8 -= 4096; }
    else if (off8 < 20480) { src = Wq; dst = oq; off8 -= 12288; }
    else                   { src = Wk; dst = ok; off8 -= 20480; }
    const int e = off8 * 8;
    f32x4 a = *(const f32x4*)(src + e);
    f32x4 b = *(const f32x4*)(src + e + 4);
    U8 pk;
#pragma unroll
    for (int j = 0; j < 4; j++) { pk.u[j] = f2bf(a[j]); pk.u[4 + j] = f2bf(b[j]); }
    *(short8*)(dst + e) = pk.v;
  }
}

// ---------------------------------------------------------------------------
// gemm_full2<K,AF32>: C[m0:+128, 0:256] = act(A[M,K] @ W[256,K]^T + b) -> bf16
// BK=32 double-buffered 2-phase: stage(t+1) issued BEFORE compute(t); one
// barrier per K-step. LDS: 2 x (A 8K + B 16K) = 48 KB. 64-B rows, XOR swizzle
// ^((row&3)<<4) both-sides. setprio around the MFMA cluster (T5).
// acc0+acc1 = 128 VGPRs, launch_bounds(256,2): no spill.
// ---------------------------------------------------------------------------
template<int K, bool AF32>
__device__ __forceinline__ void gemm_full2(
    const void* __restrict__ Ain, const u16* __restrict__ W,
    const float* __restrict__ bias, u16* __restrict__ C,
    const int m0, const bool relu, char* smem) {
  const int tid = threadIdx.x;
  const int lane = tid & 63, wid = tid >> 6;
  const int wr = wid >> 1, wc = wid & 1;
  const int ro = lane & 15, hi = lane >> 4;

  f32x4 acc0[4][4], acc1[4][4];
#pragma unroll
  for (int m = 0; m < 4; m++)
#pragma unroll
    for (int n = 0; n < 4; n++) {
      acc0[m][n] = (f32x4){0.f, 0.f, 0.f, 0.f};
      acc1[m][n] = (f32x4){0.f, 0.f, 0.f, 0.f};
    }

  // buffers: [buf] A 8 KB + B 16 KB
  auto stage = [&](int buf, int k0) {
    char* Ax = smem + buf * 24576;
    char* Bx = Ax + 8192;
    if (AF32) {
      const float* Af = (const float*)Ain;
#pragma unroll
      for (int it = 0; it < 2; it++) {
        const int e = (tid + it * 256) * 8;      // elem in 128x32 tile
        const int r = e >> 5, c = e & 31;
        const float* s = Af + (size_t)(m0 + r) * K + k0 + c;
        f32x4 a = *(const f32x4*)s, b = *(const f32x4*)(s + 4);
        U8 pk;
#pragma unroll
        for (int j = 0; j < 4; j++) { pk.u[j] = f2bf(a[j]); pk.u[4 + j] = f2bf(b[j]); }
        *(short8*)(Ax + ((r * 64 + c * 2) ^ ((r & 3) << 4))) = pk.v;
      }
    } else {
      const u16* Ab = (const u16*)Ain;
#pragma unroll
      for (int i = 0; i < 2; i++) {
        const int boff = i * 4096 + wid * 1024;
        const int t = boff + lane * 16;
        const int row = t >> 6;
        const int cb = (t & 63) ^ ((row & 3) << 4);
        cp16(Ab + (size_t)(m0 + row) * K + k0 + (cb >> 1), Ax + boff);
      }
    }
#pragma unroll
    for (int i = 0; i < 4; i++) {
      const int boff = i * 4096 + wid * 1024;
      const int t = boff + lane * 16;
      const int row = t >> 6;
      const int cb = (t & 63) ^ ((row & 3) << 4);
      cp16(W + (size_t)row * K + k0 + (cb >> 1), Bx + boff);
    }
  };

  auto compute = [&](int buf) {
    char* Ax = smem + buf * 24576;
    char* Bx = Ax + 8192;
    short8 af[4], fb0[4], fb1[4];
#pragma unroll
    for (int m = 0; m < 4; m++) {
      const int row = wr * 64 + m * 16 + ro;
      af[m] = *(const short8*)(Ax + ((row * 64 + hi * 16) ^ ((row & 3) << 4)));
    }
#pragma unroll
    for (int n = 0; n < 4; n++) {
      const int r0 = wc * 64 + n * 16 + ro;
      fb0[n] = *(const short8*)(Bx + ((r0 * 64 + hi * 16) ^ ((r0 & 3) << 4)));
      const int r1 = 128 + r0;
      fb1[n] = *(const short8*)(Bx + ((r1 * 64 + hi * 16) ^ ((r1 & 3) << 4)));
    }
    __builtin_amdgcn_s_setprio(1);
#pragma unroll
    for (int m = 0; m < 4; m++)
#pragma unroll
      for (int n = 0; n < 4; n++) {
        acc0[m][n] = MFMA16(af[m], fb0[n], acc0[m][n], 0, 0, 0);
        acc1[m][n] = MFMA16(af[m], fb1[n], acc1[m][n], 0, 0, 0);
      }
    __builtin_amdgcn_s_setprio(0);
  };

  stage(0, 0);
  __syncthreads();
  int cur = 0;
  for (int k0 = 32; k0 < K; k0 += 32) {
    stage(cur ^ 1, k0);       // loads fly under compute(cur)
    compute(cur);
    __syncthreads();          // stage landed
    cur ^= 1;
  }
  compute(cur);
  __syncthreads();

  // epilogue through LDS for coalesced stores
  u16 (*Cs)[136] = (u16(*)[136])smem;
  auto ep = [&](f32x4 (&acc)[4][4], const int n0) {
#pragma unroll
    for (int half = 0; half < 2; half++) {
      if (wr == half) {
#pragma unroll
        for (int n = 0; n < 4; n++) {
          const int col = wc * 64 + n * 16 + ro;
          const float bb = bias[n0 + col];
#pragma unroll
          for (int m = 0; m < 4; m++)
#pragma unroll
            for (int j = 0; j < 4; j++) {
              float val = acc[m][n][j] + bb;
              if (relu) val = fmaxf(val, 0.f);
              Cs[m * 16 + hi * 4 + j][col] = f2bf(val);
            }
        }
      }
      __syncthreads();
      for (int i = tid; i < 64 * 16; i += 256) {
        const int r = i >> 4, c = (i & 15) << 3;
        *(short8*)(C + (size_t)(m0 + half * 64 + r) * 256 + n0 + c) = *(short8*)&Cs[r][c];
      }
      __syncthreads();
    }
  };
  ep(acc0, 0);
  ep(acc1, 128);
}

// ---------------------------------------------------------------------------
// L2: gemm1 x1 = relu(obs@W1^T+b1), fp32 A converted in staging (blocks
// 0..511, K=128) + prep2 (512..527)
// ---------------------------------------------------------------------------
__global__ __launch_bounds__(256, 2) void k_gemm1_prep2(
    const float* __restrict__ obs, const u16* __restrict__ W1b,
    const float* __restrict__ b1, u16* __restrict__ x1,
    const float* __restrict__ W3, const float* __restrict__ M1,
    const float* __restrict__ bvchain, const float* __restrict__ bvw,
    float* __restrict__ Wzf, float* __restrict__ bz) {
  __shared__ char smem[49152];
  if (blockIdx.x < 512) {
    gemm_full2<128, true>(obs, W1b, b1, x1, (int)blockIdx.x * 128, true, smem);
    return;
  }
  float* w3r = (float*)smem;
  float* red = (float*)(smem + 1024);
  const int a = blockIdx.x - 512, d = threadIdx.x;
  w3r[d] = W3[a * 256 + d];
  __syncthreads();
  float acc = 0.f;
  for (int j = 0; j < 256; j++) acc += w3r[j] * M1[j * 256 + d];
  Wzf[a * 256 + d] = acc;
  float p = w3r[d] * bvchain[d] + acc * bvw[d];
  for (int off = 32; off >= 1; off >>= 1) p += __shfl_xor(p, off);
  if ((d & 63) == 0) red[d >> 6] = p;
  __syncthreads();
  if (d == 0) bz[a] = red[0] + red[1] + red[2] + red[3];
}

// ---------------------------------------------------------------------------
// L3: x2 = relu(x1@W2^T+b2) (blocks 0..511) + prep3 (512..575)
// ---------------------------------------------------------------------------
__global__ __launch_bounds__(256, 2) void k_x2_prep3(
    const u16* __restrict__ x1, const u16* __restrict__ W2b,
    const float* __restrict__ b2, u16* __restrict__ x2,
    const float* __restrict__ Wzf, const float* __restrict__ Wv,
    u16* __restrict__ G) {
  __shared__ char smem[49152];
  if (blockIdx.x < 512) {
    gemm_full2<256, false>(x1, W2b, b2, x2, (int)blockIdx.x * 128, true, smem);
    return;
  }
  const int g = blockIdx.x - 512, d2 = threadIdx.x;
  const int h = g >> 4, a = g & 15;
  float* wzr = (float*)smem;
  if (d2 < 64) wzr[d2] = Wzf[a * 256 + h * 64 + d2];
  __syncthreads();
  float acc = 0.f;
#pragma unroll 8
  for (int d = 0; d < 64; d++) acc += wzr[d] * Wv[(size_t)(h * 64 + d) * 256 + d2];
  G[g * 256 + d2] = f2bf(acc);
}

// ---------------------------------------------------------------------------
// L4: Q/K full-row tiles, XCD-paired (blocks 0..1023) + gemmv 2-phase
// (1024..1535)
// ---------------------------------------------------------------------------
__global__ __launch_bounds__(256, 2) void k_qk_gemmv(
    const u16* __restrict__ x2,
    const u16* __restrict__ Wqb, const float* __restrict__ bq, u16* __restrict__ Qg,
    const u16* __restrict__ Wkb, const float* __restrict__ bk, u16* __restrict__ Kg,
    const u16* __restrict__ G, u16* __restrict__ Vzt) {
  __shared__ char smem[49152];
  const int bid = blockIdx.x;
  if (bid < 1024) {
    const int q = bid >> 4, r = bid & 15;
    const int mt = q * 8 + (r & 7);
    const int sub = r >> 3;
    gemm_full2<256, false>(x2, sub ? Wkb : Wqb, sub ? bk : bq, sub ? Kg : Qg,
                           mt * 128, false, smem);
    return;
  }
  // ---- gemmv: Vz[M,64] = x2 @ G[64,256]^T, BK=32 dbuf, transposed store ----
  const int tid = threadIdx.x;
  const int lane = tid & 63, w = tid >> 6;
  const int ro = lane & 15, hi = lane >> 4;
  const int m0 = (bid - 1024) * 128;

  f32x4 acc[2][4];
#pragma unroll
  for (int m = 0; m < 2; m++)
#pragma unroll
    for (int n = 0; n < 4; n++) acc[m][n] = (f32x4){0.f, 0.f, 0.f, 0.f};

  // buffers: [buf] A 8 KB + B 4 KB (12 KB stride)
  auto stage = [&](int buf, int k0) {
    char* Ax = smem + buf * 12288;
    char* Bx = Ax + 8192;
#pragma unroll
    for (int i = 0; i < 2; i++) {
      const int boff = i * 4096 + w * 1024;
      const int t = boff + lane * 16;
      const int row = t >> 6;
      const int cb = (t & 63) ^ ((row & 3) << 4);
      cp16(x2 + (size_t)(m0 + row) * 256 + k0 + (cb >> 1), Ax + boff);
    }
    {
      const int boff = w * 1024;
      const int t = boff + lane * 16;
      const int row = t >> 6;
      const int cb = (t & 63) ^ ((row & 3) << 4);
      cp16(G + (size_t)row * 256 + k0 + (cb >> 1), Bx + boff);
    }
  };
  auto compute = [&](int buf) {
    char* Ax = smem + buf * 12288;
    char* Bx = Ax + 8192;
    short8 af[2], fb[4];
#pragma unroll
    for (int m = 0; m < 2; m++) {
      const int row = w * 32 + m * 16 + ro;
      af[m] = *(const short8*)(Ax + ((row * 64 + hi * 16) ^ ((row & 3) << 4)));
    }
#pragma unroll
    for (int n = 0; n < 4; n++) {
      const int row = n * 16 + ro;
      fb[n] = *(const short8*)(Bx + ((row * 64 + hi * 16) ^ ((row & 3) << 4)));
    }
    __builtin_amdgcn_s_setprio(1);
#pragma unroll
    for (int m = 0; m < 2; m++)
#pragma unroll
      for (int n = 0; n < 4; n++)
        acc[m][n] = MFMA16(af[m], fb[n], acc[m][n], 0, 0, 0);
    __builtin_amdgcn_s_setprio(0);
  };

  stage(0, 0);
  __syncthreads();
  int cur = 0;
  for (int k0 = 32; k0 < 256; k0 += 32) {
    stage(cur ^ 1, k0);
    compute(cur);
    __syncthreads();
    cur ^= 1;
  }
  compute(cur);

#pragma unroll
  for (int m = 0; m < 2; m++) {
    const int rbase = w * 32 + m * 16;
    const int bidx = (m0 >> 6) + (rbase >> 6);
    const int ke = (rbase + hi * 4) & 63;
#pragma unroll
    for (int n = 0; n < 4; n++) {
      const int c = n * 16 + ro;
      U4 pk;
#pragma unroll
      for (int j = 0; j < 4; j++) pk.u[j] = f2bf(acc[m][n][j]);
      *(u64*)(Vzt + (size_t)bidx * 4096 + (size_t)c * 64 + ke) = pk.v;
    }
  }
}

// ---------------------------------------------------------------------------
// attn_fused: per b. QK^T -> masked in-register softmax -> P@Vz ->
// cross-head Z reduce -> out = adj@Z + b3 + deg*bz.
// ---------------------------------------------------------------------------
__global__ __launch_bounds__(256, 2) void attn_fused(
    const u16* __restrict__ Qg, const u16* __restrict__ Kg,
    const u16* __restrict__ Vzt, const float* __restrict__ adj,
    const float* __restrict__ bz, const float* __restrict__ b3,
    float* __restrict__ out) {
  __shared__ u16 Ps[4][64][72];
  __shared__ float Zs[4][64][16];
  __shared__ u64 adjm[64];
  __shared__ u16 chunk[64][4];

  const int b = blockIdx.x, tid = threadIdx.x;
  const int lane = tid & 63, w = tid >> 6;
  const int ro = lane & 15, hi = lane >> 4;
  const int hc = w * 64;
  const size_t base = (size_t)b * 64 * 256;

  short8 kb[4][2];
#pragma unroll
  for (int n = 0; n < 4; n++)
#pragma unroll
    for (int ks = 0; ks < 2; ks++)
      kb[n][ks] = *(const short8*)(Kg + base + (size_t)(n * 16 + ro) * 256 + hc + ks * 32 + hi * 8);

  {
    const int q = tid >> 2, qa = tid & 3;
    const float* ar = adj + ((size_t)b * 64 + q) * 64 + qa * 16;
    f32x4 a0 = *(const f32x4*)(ar);
    f32x4 a1 = *(const f32x4*)(ar + 4);
    f32x4 a2 = *(const f32x4*)(ar + 8);
    f32x4 a3 = *(const f32x4*)(ar + 12);
    unsigned m16 = 0;
#pragma unroll
    for (int i = 0; i < 4; i++) {
      m16 |= (unsigned)(a0[i] != 0.f) << i;
      m16 |= (unsigned)(a1[i] != 0.f) << (4 + i);
      m16 |= (unsigned)(a2[i] != 0.f) << (8 + i);
      m16 |= (unsigned)(a3[i] != 0.f) << (12 + i);
    }
    chunk[q][qa] = (u16)m16;
  }

  f32x4 s[4][4];
#pragma unroll
  for (int m = 0; m < 4; m++) {
    short8 af[2];
#pragma unroll
    for (int ks = 0; ks < 2; ks++)
      af[ks] = *(const short8*)(Qg + base + (size_t)(m * 16 + ro) * 256 + hc + ks * 32 + hi * 8);
#pragma unroll
    for (int n = 0; n < 4; n++) s[m][n] = (f32x4){0.f, 0.f, 0.f, 0.f};
#pragma unroll
    for (int ks = 0; ks < 2; ks++)
#pragma unroll
      for (int n = 0; n < 4; n++)
        s[m][n] = MFMA16(af[ks], kb[n][ks], s[m][n], 0, 0, 0);
  }

  short8 vz[2];
#pragma unroll
  for (int ks = 0; ks < 2; ks++)
    vz[ks] = *(const short8*)(Vzt + (size_t)b * 4096 + (size_t)(hc / 4 + ro) * 64 + ks * 32 + hi * 8);

  __syncthreads();
  if (tid < 64)
    adjm[tid] = (u64)chunk[tid][0] | ((u64)chunk[tid][1] << 16) |
                ((u64)chunk[tid][2] << 32) | ((u64)chunk[tid][3] << 48);
  __syncthreads();

#pragma unroll
  for (int m = 0; m < 4; m++) {
#pragma unroll
    for (int j = 0; j < 4; j++) {
      const int q = m * 16 + hi * 4 + j;
      const u64 msk = adjm[q];
      float sv[4], ev[4];
      float mx = -3.0e38f;
#pragma unroll
      for (int n = 0; n < 4; n++) {
        const bool on = (msk >> (n * 16 + ro)) & 1ull;
        sv[n] = on ? s[m][n][j] * 0.125f : -3.0e38f;
        mx = fmaxf(mx, sv[n]);
      }
      mx = fmaxf(mx, __shfl_xor(mx, 1));
      mx = fmaxf(mx, __shfl_xor(mx, 2));
      mx = fmaxf(mx, __shfl_xor(mx, 4));
      mx = fmaxf(mx, __shfl_xor(mx, 8));
      float sum = 0.f;
#pragma unroll
      for (int n = 0; n < 4; n++) {
        ev[n] = (sv[n] > -1.0e37f) ? __expf(sv[n] - mx) : 0.f;
        sum += ev[n];
      }
      sum += __shfl_xor(sum, 1);
      sum += __shfl_xor(sum, 2);
      sum += __shfl_xor(sum, 4);
      sum += __shfl_xor(sum, 8);
      const float inv = 1.0f / sum;
#pragma unroll
      for (int n = 0; n < 4; n++)
        Ps[w][q][n * 16 + ro] = f2bf(ev[n] * inv);
    }
  }

#pragma unroll
  for (int m = 0; m < 4; m++) {
    short8 pa[2];
    pa[0] = *(const short8*)&Ps[w][m * 16 + ro][hi * 8];
    pa[1] = *(const short8*)&Ps[w][m * 16 + ro][32 + hi * 8];
    f32x4 oz = (f32x4){0.f, 0.f, 0.f, 0.f};
#pragma unroll
    for (int ks = 0; ks < 2; ks++)
      oz = MFMA16(pa[ks], vz[ks], oz, 0, 0, 0);
#pragma unroll
    for (int j = 0; j < 4; j++)
      Zs[w][m * 16 + hi * 4 + j][ro] = oz[j];
  }
  __syncthreads();

  for (int i = tid; i < 1024; i += 256) {
    const int r = i >> 4, a = i & 15;
    Zs[0][r][a] += Zs[1][r][a] + Zs[2][r][a] + Zs[3][r][a];
  }
  __syncthreads();

  {
    const int n = tid >> 2, a4 = (tid & 3) << 2;
    const u64 msk = adjm[n];
    const float deg = (float)__popcll(msk);
    float a0 = 0.f, a1 = 0.f, a2 = 0.f, a3 = 0.f;
#pragma unroll 8
    for (int m = 0; m < 64; m++) {
      const float wv = (float)((msk >> m) & 1ull);
      f32x4 z = *(const f32x4*)&Zs[0][m][a4];
      a0 += wv * z[0]; a1 += wv * z[1]; a2 += wv * z[2]; a3 += wv * z[3];
    }
    f32x4 r;
    r[0] = a0 + b3[a4 + 0] + deg * bz[a4 + 0];
    r[1] = a1 + b3[a4 + 1] + deg * bz[a4 + 1];
    r[2] = a2 + b3[a4 + 2] + deg * bz[a4 + 2];
    r[3] = a3 + b3[a4 + 3] + deg * bz[a4 + 3];
    *(f32x4*)(out + ((size_t)b * 64 + n) * 16 + a4) = r;
  }
}

// ---------------------------------------------------------------------------
extern "C" void kernel_launch(void* const* d_in, const int* in_sizes, int n_in,
                              void* d_out, int out_size, void* d_ws, size_t ws_size,
                              hipStream_t stream) {
  const float* obs = (const float*)d_in[0];
  const float* adj = (const float*)d_in[1];
  const float* W1  = (const float*)d_in[2];
  const float* b1  = (const float*)d_in[3];
  const float* W2  = (const float*)d_in[4];
  const float* b2  = (const float*)d_in[5];
  const float* Wq  = (const float*)d_in[6];
  const float* bq  = (const float*)d_in[7];
  const float* Wk  = (const float*)d_in[8];
  const float* bk  = (const float*)d_in[9];
  const float* Wv  = (const float*)d_in[10];
  const float* bvw = (const float*)d_in[11];
  const float* Wo  = (const float*)d_in[12];
  const float* bo  = (const float*)d_in[13];
  const float* Wc  = (const float*)d_in[14];
  const float* bc  = (const float*)d_in[15];
  const float* W3  = (const float*)d_in[16];
  const float* b3  = (const float*)d_in[17];
  float* out = (float*)d_out;

  char* ws = (char*)d_ws;
  const size_t BIG = (size_t)MTOT * 256 * 2;       // 33.5 MB
  u16* buf0 = (u16*)(ws);                          // x1, then Vzt (x1 dead)
  u16* buf1 = (u16*)(ws + BIG);                    // x2
  u16* buf2 = (u16*)(ws + 2 * BIG);                // Q
  u16* buf3 = (u16*)(ws + 3 * BIG);                // K
  char* p = ws + 4 * BIG;
  u16* W1b = (u16*)p;              p += 128 * 256 * 2;
  u16* W2b = (u16*)p;              p += 256 * 256 * 2;
  u16* Wqb = (u16*)p;              p += 256 * 256 * 2;
  u16* Wkb = (u16*)p;              p += 256 * 256 * 2;
  float* M1 = (float*)p;           p += 256 * 256 * 4;
  float* Wzf = (float*)p;          p += 16 * 256 * 4;
  u16* G   = (u16*)p;              p += 64 * 256 * 2;
  float* bv = (float*)p;           p += 256 * 4;
  float* bz = (float*)p;           p += 16 * 4;

  dim3 blk(256);
  k_l1<<<dim3(368), blk, 0, stream>>>(Wc, Wo, bo, bc, M1, bv,
                                      W1, W2, Wq, Wk, W1b, W2b, Wqb, Wkb);
  k_gemm1_prep2<<<dim3(528), blk, 0, stream>>>(obs, W1b, b1, buf0,
                                               W3, M1, bv, bvw, Wzf, bz);
  k_x2_prep3<<<dim3(576), blk, 0, stream>>>(buf0, W2b, b2, buf1, Wzf, Wv, G);
  k_qk_gemmv<<<dim3(1536), blk, 0, stream>>>(buf1, Wqb, bq, buf2,
                                             Wkb, bk, buf3, G, buf0);
  attn_fused<<<dim3(1024), blk, 0, stream>>>(buf2, buf3, buf0, adj, bz, b3, out);
}

// Round 11
// 120.635 us; speedup vs baseline: 1.2830x; 1.0155x over previous
//
#include <hip/hip_runtime.h>
#include <stdint.h>

typedef unsigned short u16;
typedef unsigned long long u64;
typedef __attribute__((ext_vector_type(8))) short short8;
typedef __attribute__((ext_vector_type(4))) float f32x4;

#define MFMA16 __builtin_amdgcn_mfma_f32_16x16x32_bf16

#define MTOT 65536   // B*N = 1024*64

__device__ __forceinline__ u16 f2bf(float f) {
  union { float f; uint32_t u; } v; v.f = f;
  uint32_t r = v.u + 0x7FFFu + ((v.u >> 16) & 1u);
  return (u16)(r >> 16);
}

union U8 { short8 v; u16 u[8]; };
union U4 { u64 v; u16 u[4]; };

__device__ __forceinline__ void cp16(const void* g, void* l) {
  __builtin_amdgcn_global_load_lds(
      (const __attribute__((address_space(1))) void*)g,
      (__attribute__((address_space(3))) void*)l, 16, 0, 0);
}

// 64-B-row LDS swizzle: chunk ^= (row>>1)&3  (16 rows -> 8 bank-groups x2 = free)
__device__ __forceinline__ int swz(int row) { return ((row >> 1) & 3) << 4; }

// ---------------------------------------------------------------------------
// L1: prep1 (blocks 0..255) + wconv of W1,W2,Wq,Wk (blocks 256..367)
// ---------------------------------------------------------------------------
__global__ __launch_bounds__(256) void k_l1(
    const float* __restrict__ Wc, const float* __restrict__ Wo,
    const float* __restrict__ bo, const float* __restrict__ bc,
    float* __restrict__ M1, float* __restrict__ bv,
    const float* __restrict__ W1, const float* __restrict__ W2,
    const float* __restrict__ Wq, const float* __restrict__ Wk,
    u16* o1, u16* o2, u16* oq, u16* ok) {
  const int bid = blockIdx.x, tid = threadIdx.x;
  if (bid < 256) {
    __shared__ float wcr[256];
    __shared__ float red[4];
    const int j = bid, d = tid;
    wcr[d] = Wc[j * 256 + d];
    __syncthreads();
    float acc = 0.f;
    for (int i = 0; i < 256; i++) acc += wcr[i] * Wo[i * 256 + d];
    M1[j * 256 + d] = acc;
    float p = wcr[d] * bo[d];
    for (int off = 32; off >= 1; off >>= 1) p += __shfl_xor(p, off);
    if ((d & 63) == 0) red[d >> 6] = p;
    __syncthreads();
    if (d == 0) bv[j] = bc[j] + red[0] + red[1] + red[2] + red[3];
  } else {
    int off8 = (bid - 256) * 256 + tid;
    const float* src; u16* dst;
    if      (off8 <  4096) { src = W1; dst = o1; }
    else if (off8 < 12288) { src = W2; dst = o2; off8 -= 4096; }
    else if (off8 < 20480) { src = Wq; dst = oq; off8 -= 12288; }
    else                   { src = Wk; dst = ok; off8 -= 20480; }
    const int e = off8 * 8;
    f32x4 a = *(const f32x4*)(src + e);
    f32x4 b = *(const f32x4*)(src + e + 4);
    U8 pk;
#pragma unroll
    for (int j = 0; j < 4; j++) { pk.u[j] = f2bf(a[j]); pk.u[4 + j] = f2bf(b[j]); }
    *(short8*)(dst + e) = pk.v;
  }
}

// ---------------------------------------------------------------------------
// gemm_full2<K,AF32>: C[m0:+128, 0:256] = act(A[M,K] @ W[256,K]^T + b) -> bf16
// BK=32 double-buffered. Non-AF32 path: T4 counted-vmcnt pipeline —
// stage(t+2) issued after post-compute barrier; pre-compute wait is
// vmcnt(6) (tile-t retired, tile-t+1 still in flight), raw s_barrier (no
// drain). AF32 (gemm1): plain __syncthreads loop (reg-staged A pollutes the
// vm count). LDS: 2 x 24 KB. acc0+acc1 = 128 VGPRs, launch_bounds(256,2).
// ---------------------------------------------------------------------------
template<int K, bool AF32>
__device__ __forceinline__ void gemm_full2(
    const void* __restrict__ Ain, const u16* __restrict__ W,
    const float* __restrict__ bias, u16* __restrict__ C,
    const int m0, const bool relu, char* smem) {
  const int tid = threadIdx.x;
  const int lane = tid & 63, wid = tid >> 6;
  const int wr = wid >> 1, wc = wid & 1;
  const int ro = lane & 15, hi = lane >> 4;

  f32x4 acc0[4][4], acc1[4][4];
#pragma unroll
  for (int m = 0; m < 4; m++)
#pragma unroll
    for (int n = 0; n < 4; n++) {
      acc0[m][n] = (f32x4){0.f, 0.f, 0.f, 0.f};
      acc1[m][n] = (f32x4){0.f, 0.f, 0.f, 0.f};
    }

  // buffers: [buf] A 8 KB + B 16 KB
  auto stage = [&](int buf, int k0) {
    char* Ax = smem + buf * 24576;
    char* Bx = Ax + 8192;
    if (AF32) {
      const float* Af = (const float*)Ain;
#pragma unroll
      for (int it = 0; it < 2; it++) {
        const int e = (tid + it * 256) * 8;      // elem in 128x32 tile
        const int r = e >> 5, c = e & 31;
        const float* s = Af + (size_t)(m0 + r) * K + k0 + c;
        f32x4 a = *(const f32x4*)s, b = *(const f32x4*)(s + 4);
        U8 pk;
#pragma unroll
        for (int j = 0; j < 4; j++) { pk.u[j] = f2bf(a[j]); pk.u[4 + j] = f2bf(b[j]); }
        *(short8*)(Ax + ((r * 64 + c * 2) ^ swz(r))) = pk.v;
      }
    } else {
      const u16* Ab = (const u16*)Ain;
#pragma unroll
      for (int i = 0; i < 2; i++) {
        const int boff = i * 4096 + wid * 1024;
        const int t = boff + lane * 16;
        const int row = t >> 6;
        const int cb = (t & 63) ^ swz(row);
        cp16(Ab + (size_t)(m0 + row) * K + k0 + (cb >> 1), Ax + boff);
      }
    }
#pragma unroll
    for (int i = 0; i < 4; i++) {
      const int boff = i * 4096 + wid * 1024;
      const int t = boff + lane * 16;
      const int row = t >> 6;
      const int cb = (t & 63) ^ swz(row);
      cp16(W + (size_t)row * K + k0 + (cb >> 1), Bx + boff);
    }
  };

  auto compute = [&](int buf) {
    char* Ax = smem + buf * 24576;
    char* Bx = Ax + 8192;
    short8 af[4], fb0[4], fb1[4];
#pragma unroll
    for (int m = 0; m < 4; m++) {
      const int row = wr * 64 + m * 16 + ro;
      af[m] = *(const short8*)(Ax + ((row * 64 + hi * 16) ^ swz(row)));
    }
#pragma unroll
    for (int n = 0; n < 4; n++) {
      const int r0 = wc * 64 + n * 16 + ro;
      fb0[n] = *(const short8*)(Bx + ((r0 * 64 + hi * 16) ^ swz(r0)));
      const int r1 = 128 + r0;
      fb1[n] = *(const short8*)(Bx + ((r1 * 64 + hi * 16) ^ swz(r1)));
    }
    __builtin_amdgcn_s_setprio(1);
#pragma unroll
    for (int m = 0; m < 4; m++)
#pragma unroll
      for (int n = 0; n < 4; n++) {
        acc0[m][n] = MFMA16(af[m], fb0[n], acc0[m][n], 0, 0, 0);
        acc1[m][n] = MFMA16(af[m], fb1[n], acc1[m][n], 0, 0, 0);
      }
    __builtin_amdgcn_s_setprio(0);
  };

  constexpr int NT = K / 32;
  if (AF32) {
    stage(0, 0);
    __syncthreads();
    int cur = 0;
    for (int k0 = 32; k0 < K; k0 += 32) {
      stage(cur ^ 1, k0);
      compute(cur);
      __syncthreads();
      cur ^= 1;
    }
    compute(cur);
    __syncthreads();
  } else {
    stage(0, 0);
    stage(1, 32);
#pragma unroll
    for (int t = 0; t < NT; ++t) {
      if (t == NT - 1) asm volatile("s_waitcnt vmcnt(0)" ::: "memory");
      else             asm volatile("s_waitcnt vmcnt(6)" ::: "memory");
      asm volatile("s_barrier" ::: "memory");
      compute(t & 1);
      asm volatile("s_barrier" ::: "memory");
      if (t + 2 < NT) stage(t & 1, (t + 2) * 32);
    }
  }

  // epilogue through LDS for coalesced stores
  u16 (*Cs)[136] = (u16(*)[136])smem;
  auto ep = [&](f32x4 (&acc)[4][4], const int n0) {
#pragma unroll
    for (int half = 0; half < 2; half++) {
      if (wr == half) {
#pragma unroll
        for (int n = 0; n < 4; n++) {
          const int col = wc * 64 + n * 16 + ro;
          const float bb = bias[n0 + col];
#pragma unroll
          for (int m = 0; m < 4; m++)
#pragma unroll
            for (int j = 0; j < 4; j++) {
              float val = acc[m][n][j] + bb;
              if (relu) val = fmaxf(val, 0.f);
              Cs[m * 16 + hi * 4 + j][col] = f2bf(val);
            }
        }
      }
      __syncthreads();
      for (int i = tid; i < 64 * 16; i += 256) {
        const int r = i >> 4, c = (i & 15) << 3;
        *(short8*)(C + (size_t)(m0 + half * 64 + r) * 256 + n0 + c) = *(short8*)&Cs[r][c];
      }
      __syncthreads();
    }
  };
  ep(acc0, 0);
  ep(acc1, 128);
}

// ---------------------------------------------------------------------------
// L2: gemm1 x1 = relu(obs@W1^T+b1), fp32 A converted in staging (blocks
// 0..511, K=128) + prep2 (512..527)
// ---------------------------------------------------------------------------
__global__ __launch_bounds__(256, 2) void k_gemm1_prep2(
    const float* __restrict__ obs, const u16* __restrict__ W1b,
    const float* __restrict__ b1, u16* __restrict__ x1,
    const float* __restrict__ W3, const float* __restrict__ M1,
    const float* __restrict__ bvchain, const float* __restrict__ bvw,
    float* __restrict__ Wzf, float* __restrict__ bz) {
  __shared__ char smem[49152];
  if (blockIdx.x < 512) {
    gemm_full2<128, true>(obs, W1b, b1, x1, (int)blockIdx.x * 128, true, smem);
    return;
  }
  float* w3r = (float*)smem;
  float* red = (float*)(smem + 1024);
  const int a = blockIdx.x - 512, d = threadIdx.x;
  w3r[d] = W3[a * 256 + d];
  __syncthreads();
  float acc = 0.f;
  for (int j = 0; j < 256; j++) acc += w3r[j] * M1[j * 256 + d];
  Wzf[a * 256 + d] = acc;
  float p = w3r[d] * bvchain[d] + acc * bvw[d];
  for (int off = 32; off >= 1; off >>= 1) p += __shfl_xor(p, off);
  if ((d & 63) == 0) red[d >> 6] = p;
  __syncthreads();
  if (d == 0) bz[a] = red[0] + red[1] + red[2] + red[3];
}

// ---------------------------------------------------------------------------
// L3: x2 = relu(x1@W2^T+b2) (blocks 0..511) + prep3 (512..575)
// ---------------------------------------------------------------------------
__global__ __launch_bounds__(256, 2) void k_x2_prep3(
    const u16* __restrict__ x1, const u16* __restrict__ W2b,
    const float* __restrict__ b2, u16* __restrict__ x2,
    const float* __restrict__ Wzf, const float* __restrict__ Wv,
    u16* __restrict__ G) {
  __shared__ char smem[49152];
  if (blockIdx.x < 512) {
    gemm_full2<256, false>(x1, W2b, b2, x2, (int)blockIdx.x * 128, true, smem);
    return;
  }
  const int g = blockIdx.x - 512, d2 = threadIdx.x;
  const int h = g >> 4, a = g & 15;
  float* wzr = (float*)smem;
  if (d2 < 64) wzr[d2] = Wzf[a * 256 + h * 64 + d2];
  __syncthreads();
  float acc = 0.f;
#pragma unroll 8
  for (int d = 0; d < 64; d++) acc += wzr[d] * Wv[(size_t)(h * 64 + d) * 256 + d2];
  G[g * 256 + d2] = f2bf(acc);
}

// ---------------------------------------------------------------------------
// L4: Q/K full-row tiles, XCD-paired (blocks 0..1023) + gemmv counted-vmcnt
// pipeline (1024..1535)
// ---------------------------------------------------------------------------
__global__ __launch_bounds__(256, 2) void k_qk_gemmv(
    const u16* __restrict__ x2,
    const u16* __restrict__ Wqb, const float* __restrict__ bq, u16* __restrict__ Qg,
    const u16* __restrict__ Wkb, const float* __restrict__ bk, u16* __restrict__ Kg,
    const u16* __restrict__ G, u16* __restrict__ Vzt) {
  __shared__ char smem[49152];
  const int bid = blockIdx.x;
  if (bid < 1024) {
    const int q = bid >> 4, r = bid & 15;
    const int mt = q * 8 + (r & 7);
    const int sub = r >> 3;
    gemm_full2<256, false>(x2, sub ? Wkb : Wqb, sub ? bk : bq, sub ? Kg : Qg,
                           mt * 128, false, smem);
    return;
  }
  // ---- gemmv: Vz[M,64] = x2 @ G[64,256]^T, BK=32 dbuf piped, transp store --
  const int tid = threadIdx.x;
  const int lane = tid & 63, w = tid >> 6;
  const int ro = lane & 15, hi = lane >> 4;
  const int m0 = (bid - 1024) * 128;

  f32x4 acc[2][4];
#pragma unroll
  for (int m = 0; m < 2; m++)
#pragma unroll
    for (int n = 0; n < 4; n++) acc[m][n] = (f32x4){0.f, 0.f, 0.f, 0.f};

  // buffers: [buf] A 8 KB + B 4 KB (12 KB stride)
  auto stage = [&](int buf, int k0) {
    char* Ax = smem + buf * 12288;
    char* Bx = Ax + 8192;
#pragma unroll
    for (int i = 0; i < 2; i++) {
      const int boff = i * 4096 + w * 1024;
      const int t = boff + lane * 16;
      const int row = t >> 6;
      const int cb = (t & 63) ^ swz(row);
      cp16(x2 + (size_t)(m0 + row) * 256 + k0 + (cb >> 1), Ax + boff);
    }
    {
      const int boff = w * 1024;
      const int t = boff + lane * 16;
      const int row = t >> 6;
      const int cb = (t & 63) ^ swz(row);
      cp16(G + (size_t)row * 256 + k0 + (cb >> 1), Bx + boff);
    }
  };
  auto compute = [&](int buf) {
    char* Ax = smem + buf * 12288;
    char* Bx = Ax + 8192;
    short8 af[2], fb[4];
#pragma unroll
    for (int m = 0; m < 2; m++) {
      const int row = w * 32 + m * 16 + ro;
      af[m] = *(const short8*)(Ax + ((row * 64 + hi * 16) ^ swz(row)));
    }
#pragma unroll
    for (int n = 0; n < 4; n++) {
      const int row = n * 16 + ro;
      fb[n] = *(const short8*)(Bx + ((row * 64 + hi * 16) ^ swz(row)));
    }
    __builtin_amdgcn_s_setprio(1);
#pragma unroll
    for (int m = 0; m < 2; m++)
#pragma unroll
      for (int n = 0; n < 4; n++)
        acc[m][n] = MFMA16(af[m], fb[n], acc[m][n], 0, 0, 0);
    __builtin_amdgcn_s_setprio(0);
  };

  stage(0, 0);
  stage(1, 32);
#pragma unroll
  for (int t = 0; t < 8; ++t) {
    if (t == 7) asm volatile("s_waitcnt vmcnt(0)" ::: "memory");
    else        asm volatile("s_waitcnt vmcnt(3)" ::: "memory");
    asm volatile("s_barrier" ::: "memory");
    compute(t & 1);
    asm volatile("s_barrier" ::: "memory");
    if (t + 2 < 8) stage(t & 1, (t + 2) * 32);
  }

#pragma unroll
  for (int m = 0; m < 2; m++) {
    const int rbase = w * 32 + m * 16;
    const int bidx = (m0 >> 6) + (rbase >> 6);
    const int ke = (rbase + hi * 4) & 63;
#pragma unroll
    for (int n = 0; n < 4; n++) {
      const int c = n * 16 + ro;
      U4 pk;
#pragma unroll
      for (int j = 0; j < 4; j++) pk.u[j] = f2bf(acc[m][n][j]);
      *(u64*)(Vzt + (size_t)bidx * 4096 + (size_t)c * 64 + ke) = pk.v;
    }
  }
}

// ---------------------------------------------------------------------------
// attn_fused: per b. QK^T -> masked in-register softmax -> P@Vz ->
// cross-head Z reduce -> out = adj@Z + b3 + deg*bz.
// ---------------------------------------------------------------------------
__global__ __launch_bounds__(256, 2) void attn_fused(
    const u16* __restrict__ Qg, const u16* __restrict__ Kg,
    const u16* __restrict__ Vzt, const float* __restrict__ adj,
    const float* __restrict__ bz, const float* __restrict__ b3,
    float* __restrict__ out) {
  __shared__ u16 Ps[4][64][72];
  __shared__ float Zs[4][64][16];
  __shared__ u64 adjm[64];
  __shared__ u16 chunk[64][4];

  const int b = blockIdx.x, tid = threadIdx.x;
  const int lane = tid & 63, w = tid >> 6;
  const int ro = lane & 15, hi = lane >> 4;
  const int hc = w * 64;
  const size_t base = (size_t)b * 64 * 256;

  short8 kb[4][2];
#pragma unroll
  for (int n = 0; n < 4; n++)
#pragma unroll
    for (int ks = 0; ks < 2; ks++)
      kb[n][ks] = *(const short8*)(Kg + base + (size_t)(n * 16 + ro) * 256 + hc + ks * 32 + hi * 8);

  {
    const int q = tid >> 2, qa = tid & 3;
    const float* ar = adj + ((size_t)b * 64 + q) * 64 + qa * 16;
    f32x4 a0 = *(const f32x4*)(ar);
    f32x4 a1 = *(const f32x4*)(ar + 4);
    f32x4 a2 = *(const f32x4*)(ar + 8);
    f32x4 a3 = *(const f32x4*)(ar + 12);
    unsigned m16 = 0;
#pragma unroll
    for (int i = 0; i < 4; i++) {
      m16 |= (unsigned)(a0[i] != 0.f) << i;
      m16 |= (unsigned)(a1[i] != 0.f) << (4 + i);
      m16 |= (unsigned)(a2[i] != 0.f) << (8 + i);
      m16 |= (unsigned)(a3[i] != 0.f) << (12 + i);
    }
    chunk[q][qa] = (u16)m16;
  }

  f32x4 s[4][4];
#pragma unroll
  for (int m = 0; m < 4; m++) {
    short8 af[2];
#pragma unroll
    for (int ks = 0; ks < 2; ks++)
      af[ks] = *(const short8*)(Qg + base + (size_t)(m * 16 + ro) * 256 + hc + ks * 32 + hi * 8);
#pragma unroll
    for (int n = 0; n < 4; n++) s[m][n] = (f32x4){0.f, 0.f, 0.f, 0.f};
#pragma unroll
    for (int ks = 0; ks < 2; ks++)
#pragma unroll
      for (int n = 0; n < 4; n++)
        s[m][n] = MFMA16(af[ks], kb[n][ks], s[m][n], 0, 0, 0);
  }

  short8 vz[2];
#pragma unroll
  for (int ks = 0; ks < 2; ks++)
    vz[ks] = *(const short8*)(Vzt + (size_t)b * 4096 + (size_t)(hc / 4 + ro) * 64 + ks * 32 + hi * 8);

  __syncthreads();
  if (tid < 64)
    adjm[tid] = (u64)chunk[tid][0] | ((u64)chunk[tid][1] << 16) |
                ((u64)chunk[tid][2] << 32) | ((u64)chunk[tid][3] << 48);
  __syncthreads();

#pragma unroll
  for (int m = 0; m < 4; m++) {
#pragma unroll
    for (int j = 0; j < 4; j++) {
      const int q = m * 16 + hi * 4 + j;
      const u64 msk = adjm[q];
      float sv[4], ev[4];
      float mx = -3.0e38f;
#pragma unroll
      for (int n = 0; n < 4; n++) {
        const bool on = (msk >> (n * 16 + ro)) & 1ull;
        sv[n] = on ? s[m][n][j] * 0.125f : -3.0e38f;
        mx = fmaxf(mx, sv[n]);
      }
      mx = fmaxf(mx, __shfl_xor(mx, 1));
      mx = fmaxf(mx, __shfl_xor(mx, 2));
      mx = fmaxf(mx, __shfl_xor(mx, 4));
      mx = fmaxf(mx, __shfl_xor(mx, 8));
      float sum = 0.f;
#pragma unroll
      for (int n = 0; n < 4; n++) {
        ev[n] = (sv[n] > -1.0e37f) ? __expf(sv[n] - mx) : 0.f;
        sum += ev[n];
      }
      sum += __shfl_xor(sum, 1);
      sum += __shfl_xor(sum, 2);
      sum += __shfl_xor(sum, 4);
      sum += __shfl_xor(sum, 8);
      const float inv = 1.0f / sum;
#pragma unroll
      for (int n = 0; n < 4; n++)
        Ps[w][q][n * 16 + ro] = f2bf(ev[n] * inv);
    }
  }

#pragma unroll
  for (int m = 0; m < 4; m++) {
    short8 pa[2];
    pa[0] = *(const short8*)&Ps[w][m * 16 + ro][hi * 8];
    pa[1] = *(const short8*)&Ps[w][m * 16 + ro][32 + hi * 8];
    f32x4 oz = (f32x4){0.f, 0.f, 0.f, 0.f};
#pragma unroll
    for (int ks = 0; ks < 2; ks++)
      oz = MFMA16(pa[ks], vz[ks], oz, 0, 0, 0);
#pragma unroll
    for (int j = 0; j < 4; j++)
      Zs[w][m * 16 + hi * 4 + j][ro] = oz[j];
  }
  __syncthreads();

  for (int i = tid; i < 1024; i += 256) {
    const int r = i >> 4, a = i & 15;
    Zs[0][r][a] += Zs[1][r][a] + Zs[2][r][a] + Zs[3][r][a];
  }
  __syncthreads();

  {
    const int n = tid >> 2, a4 = (tid & 3) << 2;
    const u64 msk = adjm[n];
    const float deg = (float)__popcll(msk);
    float a0 = 0.f, a1 = 0.f, a2 = 0.f, a3 = 0.f;
#pragma unroll 8
    for (int m = 0; m < 64; m++) {
      const float wv = (float)((msk >> m) & 1ull);
      f32x4 z = *(const f32x4*)&Zs[0][m][a4];
      a0 += wv * z[0]; a1 += wv * z[1]; a2 += wv * z[2]; a3 += wv * z[3];
    }
    f32x4 r;
    r[0] = a0 + b3[a4 + 0] + deg * bz[a4 + 0];
    r[1] = a1 + b3[a4 + 1] + deg * bz[a4 + 1];
    r[2] = a2 + b3[a4 + 2] + deg * bz[a4 + 2];
    r[3] = a3 + b3[a4 + 3] + deg * bz[a4 + 3];
    *(f32x4*)(out + ((size_t)b * 64 + n) * 16 + a4) = r;
  }
}

// ---------------------------------------------------------------------------
extern "C" void kernel_launch(void* const* d_in, const int* in_sizes, int n_in,
                              void* d_out, int out_size, void* d_ws, size_t ws_size,
                              hipStream_t stream) {
  const float* obs = (const float*)d_in[0];
  const float* adj = (const float*)d_in[1];
  const float* W1  = (const float*)d_in[2];
  const float* b1  = (const float*)d_in[3];
  const float* W2  = (const float*)d_in[4];
  const float* b2  = (const float*)d_in[5];
  const float* Wq  = (const float*)d_in[6];
  const float* bq  = (const float*)d_in[7];
  const float* Wk  = (const float*)d_in[8];
  const float* bk  = (const float*)d_in[9];
  const float* Wv  = (const float*)d_in[10];
  const float* bvw = (const float*)d_in[11];
  const float* Wo  = (const float*)d_in[12];
  const float* bo  = (const float*)d_in[13];
  const float* Wc  = (const float*)d_in[14];
  const float* bc  = (const float*)d_in[15];
  const float* W3  = (const float*)d_in[16];
  const float* b3  = (const float*)d_in[17];
  float* out = (float*)d_out;

  char* ws = (char*)d_ws;
  const size_t BIG = (size_t)MTOT * 256 * 2;       // 33.5 MB
  u16* buf0 = (u16*)(ws);                          // x1, then Vzt (x1 dead)
  u16* buf1 = (u16*)(ws + BIG);                    // x2
  u16* buf2 = (u16*)(ws + 2 * BIG);                // Q
  u16* buf3 = (u16*)(ws + 3 * BIG);                // K
  char* p = ws + 4 * BIG;
  u16* W1b = (u16*)p;              p += 128 * 256 * 2;
  u16* W2b = (u16*)p;              p += 256 * 256 * 2;
  u16* Wqb = (u16*)p;              p += 256 * 256 * 2;
  u16* Wkb = (u16*)p;              p += 256 * 256 * 2;
  float* M1 = (float*)p;           p += 256 * 256 * 4;
  float* Wzf = (float*)p;          p += 16 * 256 * 4;
  u16* G   = (u16*)p;              p += 64 * 256 * 2;
  float* bv = (float*)p;           p += 256 * 4;
  float* bz = (float*)p;           p += 16 * 4;

  dim3 blk(256);
  k_l1<<<dim3(368), blk, 0, stream>>>(Wc, Wo, bo, bc, M1, bv,
                                      W1, W2, Wq, Wk, W1b, W2b, Wqb, Wkb);
  k_gemm1_prep2<<<dim3(528), blk, 0, stream>>>(obs, W1b, b1, buf0,
                                               W3, M1, bv, bvw, Wzf, bz);
  k_x2_prep3<<<dim3(576), blk, 0, stream>>>(buf0, W2b, b2, buf1, Wzf, Wv, G);
  k_qk_gemmv<<<dim3(1536), blk, 0, stream>>>(buf1, Wqb, bq, buf2,
                                             Wkb, bk, buf3, G, buf0);
  attn_fused<<<dim3(1024), blk, 0, stream>>>(buf2, buf3, buf0, adj, bz, b3, out);
}